// Round 7
// baseline (1609.072 us; speedup 1.0000x reference)
//
#include <hip/hip_runtime.h>
#include <hip/hip_bf16.h>

typedef __bf16 bf8 __attribute__((ext_vector_type(8)));
typedef float f4 __attribute__((ext_vector_type(4)));
typedef unsigned short u16;
typedef unsigned int u32;

#define B_ 4
#define P_ 2048
#define D_ 768
#define H_ 12
#define HD_ 64
// scale * log2(e): exp(s*0.125) = exp2(s * 0.18033688)
#define EXPC_ 0.18033688011112042f

typedef const __attribute__((address_space(1))) void gvoid;
typedef __attribute__((address_space(3))) void lvoid;

__device__ __forceinline__ void gl_lds16(const u16* g, u16* l) {
  __builtin_amdgcn_global_load_lds((gvoid*)g, (lvoid*)l, 16, 0, 0);
}

__device__ __forceinline__ u16 f2bf(float f) {  // RNE
  union { float f; u32 u; } c; c.f = f;
  u32 u = c.u;
  u += 0x7fffu + ((u >> 16) & 1u);
  return (u16)(u >> 16);
}

__device__ __forceinline__ float bf2f(u16 v) {
  union { u32 u; float f; } c; c.u = (u32)v << 16; return c.f;
}

__device__ __forceinline__ uint2 pack4(f4 v) {  // truncating 4xf32 -> 4xbf16
  union { float f; u32 u; } a, b, c, d;
  a.f = v[0]; b.f = v[1]; c.f = v[2]; d.f = v[3];
  uint2 r;
  r.x = (a.u >> 16) | (b.u & 0xffff0000u);
  r.y = (c.u >> 16) | (d.u & 0xffff0000u);
  return r;
}

__device__ __forceinline__ f4 unp2(uint2 u) {
  f4 r;
  r[0] = bf2f((u16)(u.x & 0xffffu)); r[1] = bf2f((u16)(u.x >> 16));
  r[2] = bf2f((u16)(u.y & 0xffffu)); r[3] = bf2f((u16)(u.y >> 16));
  return r;
}

__device__ __forceinline__ bf8 mkbf8(f4 a, f4 b) {
  union { uint4 u; bf8 v; } c;
  uint2 l = pack4(a), h = pack4(b);
  c.u = make_uint4(l.x, l.y, h.x, h.y);
  return c.v;
}

__device__ __forceinline__ f4 mfma16(bf8 a, bf8 b, f4 c) {
  return __builtin_amdgcn_mfma_f32_16x16x32_bf16(a, b, c, 0, 0, 0);
}

#define ZERO44(acc)                    \
  {                                    \
    f4 z_ = {0.f, 0.f, 0.f, 0.f};      \
    for (int i_ = 0; i_ < 4; ++i_)     \
      for (int j_ = 0; j_ < 4; ++j_)   \
        acc[i_][j_] = z_;              \
  }

// XCD-bijective swizzle for grids with nwg % 8 == 0 (m157).
__device__ __forceinline__ int xcd_swz(int lin, int nwg) {
  return (lin & 7) * (nwg >> 3) + (lin >> 3);
}

// ---------------- transpose-cast fp32 (R,C) -> bf16 (C,R) ----------------
__global__ __launch_bounds__(256) void tcast_k(const float* __restrict__ src,
                                               u16* __restrict__ dst, int R, int C) {
  __shared__ float t[32][33];
  int c0 = blockIdx.x * 32, r0 = blockIdx.y * 32;
  int tx = threadIdx.x & 31, ty = threadIdx.x >> 5;
  #pragma unroll
  for (int i = 0; i < 32; i += 8) {
    int r = r0 + ty + i, c = c0 + tx;
    t[ty + i][tx] = (r < R && c < C) ? src[(size_t)r * C + c] : 0.f;
  }
  __syncthreads();
  #pragma unroll
  for (int i = 0; i < 32; i += 8) {
    int c = c0 + ty + i, r = r0 + tx;
    if (c < C && r < R) dst[(size_t)c * R + r] = f2bf(t[tx][ty + i]);
  }
}

// ---------------- layernorm fp32 -> bf16 (LN1) ----------------
__global__ __launch_bounds__(256) void ln_k(const float* __restrict__ x,
                                            const float* __restrict__ g,
                                            const float* __restrict__ b,
                                            u16* __restrict__ out) {
  int row = blockIdx.x;
  const float* xr = x + (size_t)row * D_;
  float v0 = xr[threadIdx.x], v1 = xr[threadIdx.x + 256], v2 = xr[threadIdx.x + 512];
  float s = v0 + v1 + v2;
  float s2 = v0 * v0 + v1 * v1 + v2 * v2;
  #pragma unroll
  for (int o = 32; o > 0; o >>= 1) {
    s += __shfl_down(s, o, 64);
    s2 += __shfl_down(s2, o, 64);
  }
  __shared__ float a[4], a2[4];
  int wv = threadIdx.x >> 6;
  if ((threadIdx.x & 63) == 0) { a[wv] = s; a2[wv] = s2; }
  __syncthreads();
  s = a[0] + a[1] + a[2] + a[3];
  s2 = a2[0] + a2[1] + a2[2] + a2[3];
  float mean = s * (1.f / 768.f);
  float var = s2 * (1.f / 768.f) - mean * mean;
  float rstd = rsqrtf(var + 1e-5f);
  u16* orow = out + (size_t)row * D_;
  float vv[3] = {v0, v1, v2};
  #pragma unroll
  for (int j = 0; j < 3; ++j) {
    int i = threadIdx.x + j * 256;
    orow[i] = f2bf((vv[j] - mean) * rstd * g[i] + b[i]);
  }
}

// ---------------- x2 = x + O0 + O1; hln = LN(x2) ----------------
__global__ __launch_bounds__(256) void ln2add_k(const float* __restrict__ x,
                                                const u16* __restrict__ O0,
                                                const u16* __restrict__ O1,
                                                const float* __restrict__ g,
                                                const float* __restrict__ b,
                                                float* __restrict__ x2,
                                                u16* __restrict__ out) {
  int row = blockIdx.x;
  const float* xr = x + (size_t)row * D_;
  const u16* o0 = O0 + (size_t)row * D_;
  const u16* o1 = O1 + (size_t)row * D_;
  float vv[3];
  #pragma unroll
  for (int j = 0; j < 3; ++j) {
    int i = threadIdx.x + j * 256;
    vv[j] = xr[i] + bf2f(o0[i]) + bf2f(o1[i]);
  }
  float s = vv[0] + vv[1] + vv[2];
  float s2 = vv[0] * vv[0] + vv[1] * vv[1] + vv[2] * vv[2];
  #pragma unroll
  for (int o = 32; o > 0; o >>= 1) {
    s += __shfl_down(s, o, 64);
    s2 += __shfl_down(s2, o, 64);
  }
  __shared__ float a[4], a2[4];
  int wv = threadIdx.x >> 6;
  if ((threadIdx.x & 63) == 0) { a[wv] = s; a2[wv] = s2; }
  __syncthreads();
  s = a[0] + a[1] + a[2] + a[3];
  s2 = a2[0] + a2[1] + a2[2] + a2[3];
  float mean = s * (1.f / 768.f);
  float var = s2 * (1.f / 768.f) - mean * mean;
  float rstd = rsqrtf(var + 1e-5f);
  float* x2r = x2 + (size_t)row * D_;
  u16* orow = out + (size_t)row * D_;
  #pragma unroll
  for (int j = 0; j < 3; ++j) {
    int i = threadIdx.x + j * 256;
    x2r[i] = vv[j];
    orow[i] = f2bf((vv[j] - mean) * rstd * g[i] + b[i]);
  }
}

// ============ staged 128x128 GEMM core (m97 pattern), K-stride 32 ============
template <int K>
__device__ __forceinline__ void staged_core(const u16* __restrict__ Ab,
                                            const u16* __restrict__ Bb,
                                            u16* As, u16* Bs, f4 acc[4][4]) {
  const int wave = threadIdx.x >> 6, lane = threadIdx.x & 63;
  const int l15 = lane & 15, quad = lane >> 4;
  const int lrow = lane >> 2;
  const int lcol = (lane & 3) * 8;
  const int mw = (wave & 1) * 64, nw = (wave >> 1) * 64;
  for (int k0 = 0; k0 < K; k0 += 32) {
    const u16* ga = Ab + (size_t)(wave * 32 + lrow) * K + k0 + lcol;
    gl_lds16(ga, &As[(wave * 32) * 32]);
    gl_lds16(ga + (size_t)16 * K, &As[(wave * 32 + 16) * 32]);
    const u16* gb = Bb + (size_t)(wave * 32 + lrow) * K + k0 + lcol;
    gl_lds16(gb, &Bs[(wave * 32) * 32]);
    gl_lds16(gb + (size_t)16 * K, &Bs[(wave * 32 + 16) * 32]);
    __syncthreads();
    bf8 a[4], b[4];
    #pragma unroll
    for (int mt = 0; mt < 4; ++mt)
      a[mt] = *reinterpret_cast<const bf8*>(&As[(mw + mt * 16 + l15) * 32 + quad * 8]);
    #pragma unroll
    for (int nt = 0; nt < 4; ++nt)
      b[nt] = *reinterpret_cast<const bf8*>(&Bs[(nw + nt * 16 + l15) * 32 + quad * 8]);
    __builtin_amdgcn_s_setprio(1);
    #pragma unroll
    for (int mt = 0; mt < 4; ++mt)
      #pragma unroll
      for (int nt = 0; nt < 4; ++nt)
        acc[mt][nt] = mfma16(a[mt], b[nt], acc[mt][nt]);
    __builtin_amdgcn_s_setprio(0);
    __syncthreads();
  }
}

// ---------------- QKV GEMM staged ----------------
__global__ __launch_bounds__(256) void gemm_qkv_k(const u16* __restrict__ hln,
                                                  const u16* __restrict__ wT,
                                                  const float* __restrict__ bias,
                                                  u16* __restrict__ Q, u16* __restrict__ Km,
                                                  u16* __restrict__ Vt) {
  __shared__ u16 As[128 * 32], Bs[128 * 32];
  int lin = blockIdx.y * gridDim.x + blockIdx.x;
  int swz = xcd_swz(lin, gridDim.x * gridDim.y);
  int m0 = (swz / gridDim.x) * 128, n0 = (swz % gridDim.x) * 128;
  f4 acc[4][4];
  ZERO44(acc);
  staged_core<768>(hln + (size_t)m0 * 768, wT + (size_t)n0 * 768, As, Bs, acc);
  int wave = threadIdx.x >> 6, lane = threadIdx.x & 63, l15 = lane & 15, quad = lane >> 4;
  int mW = m0 + (wave & 1) * 64, nW = n0 + (wave >> 1) * 64;
  #pragma unroll
  for (int mt = 0; mt < 4; ++mt)
    #pragma unroll
    for (int nt = 0; nt < 4; ++nt)
      #pragma unroll
      for (int r = 0; r < 4; ++r) {
        int m = mW + mt * 16 + quad * 4 + r;
        int n = nW + nt * 16 + l15;
        float v = acc[mt][nt][r] + bias[n];
        u16 bv = f2bf(v);
        int b = m >> 11, p = m & 2047;
        int which = n / 768, hn = n % 768;
        int h = hn >> 6, d = hn & 63;
        if (which == 0)
          Q[((size_t)(b * H_ + h) * P_ + p) * HD_ + d] = bv;
        else if (which == 1)
          Km[((size_t)(b * H_ + h) * P_ + p) * HD_ + d] = bv;
        else
          Vt[((size_t)(b * H_ + h) * HD_ + d) * P_ + p] = bv;
      }
}

// ---------------- FC1 GEMM staged + exact GELU ----------------
__global__ __launch_bounds__(256) void gemm_fc1_k(const u16* __restrict__ A,
                                                  const u16* __restrict__ wT,
                                                  const float* __restrict__ bias,
                                                  u16* __restrict__ out) {
  __shared__ u16 As[128 * 32], Bs[128 * 32];
  int lin = blockIdx.y * gridDim.x + blockIdx.x;
  int swz = xcd_swz(lin, gridDim.x * gridDim.y);
  int m0 = (swz / gridDim.x) * 128, n0 = (swz % gridDim.x) * 128;
  f4 acc[4][4];
  ZERO44(acc);
  staged_core<768>(A + (size_t)m0 * 768, wT + (size_t)n0 * 768, As, Bs, acc);
  int wave = threadIdx.x >> 6, lane = threadIdx.x & 63, l15 = lane & 15, quad = lane >> 4;
  int mW = m0 + (wave & 1) * 64, nW = n0 + (wave >> 1) * 64;
  #pragma unroll
  for (int mt = 0; mt < 4; ++mt)
    #pragma unroll
    for (int nt = 0; nt < 4; ++nt)
      #pragma unroll
      for (int r = 0; r < 4; ++r) {
        int m = mW + mt * 16 + quad * 4 + r;
        int n = nW + nt * 16 + l15;
        float v = acc[mt][nt][r] + bias[n];
        v = 0.5f * v * (1.f + erff(v * 0.70710678f));
        out[(size_t)m * 3072 + n] = f2bf(v);
      }
}

// ---------------- FC2 GEMM staged (BM=128, BN=64), +bias +residual -> fp32 ----------------
__global__ __launch_bounds__(256) void gemm_fc2_k(const u16* __restrict__ A,
                                                  const u16* __restrict__ wT,
                                                  const float* __restrict__ bias,
                                                  const float* __restrict__ resid,
                                                  float* __restrict__ out) {
  __shared__ u16 As[128 * 32], Bs[64 * 32];
  int wave = threadIdx.x >> 6, lane = threadIdx.x & 63, l15 = lane & 15, quad = lane >> 4;
  int lrow = lane >> 2, lcol = (lane & 3) * 8;
  int lin = blockIdx.y * gridDim.x + blockIdx.x;
  int swz = xcd_swz(lin, gridDim.x * gridDim.y);
  int m0 = (swz / gridDim.x) * 128, n0 = (swz % gridDim.x) * 64;
  const u16* Ab = A + (size_t)m0 * 3072;
  const u16* Bb = wT + (size_t)n0 * 3072;
  int mw = (wave & 1) * 64, nw = (wave >> 1) * 32;
  f4 acc[4][2];
  #pragma unroll
  for (int i = 0; i < 4; ++i)
    #pragma unroll
    for (int j = 0; j < 2; ++j) acc[i][j] = f4{0.f, 0.f, 0.f, 0.f};
  for (int k0 = 0; k0 < 3072; k0 += 32) {
    const u16* ga = Ab + (size_t)(wave * 32 + lrow) * 3072 + k0 + lcol;
    gl_lds16(ga, &As[(wave * 32) * 32]);
    gl_lds16(ga + (size_t)16 * 3072, &As[(wave * 32 + 16) * 32]);
    const u16* gb = Bb + (size_t)(wave * 16 + lrow) * 3072 + k0 + lcol;
    gl_lds16(gb, &Bs[(wave * 16) * 32]);
    __syncthreads();
    bf8 a[4], b[2];
    #pragma unroll
    for (int mt = 0; mt < 4; ++mt)
      a[mt] = *reinterpret_cast<const bf8*>(&As[(mw + mt * 16 + l15) * 32 + quad * 8]);
    #pragma unroll
    for (int nt = 0; nt < 2; ++nt)
      b[nt] = *reinterpret_cast<const bf8*>(&Bs[(nw + nt * 16 + l15) * 32 + quad * 8]);
    __builtin_amdgcn_s_setprio(1);
    #pragma unroll
    for (int mt = 0; mt < 4; ++mt)
      #pragma unroll
      for (int nt = 0; nt < 2; ++nt)
        acc[mt][nt] = mfma16(a[mt], b[nt], acc[mt][nt]);
    __builtin_amdgcn_s_setprio(0);
    __syncthreads();
  }
  int mW = m0 + mw, nW = n0 + nw;
  #pragma unroll
  for (int mt = 0; mt < 4; ++mt)
    #pragma unroll
    for (int nt = 0; nt < 2; ++nt)
      #pragma unroll
      for (int r = 0; r < 4; ++r) {
        int m = mW + mt * 16 + quad * 4 + r;
        int n = nW + nt * 16 + l15;
        size_t idx = (size_t)m * 768 + n;
        out[idx] = acc[mt][nt][r] + bias[n] + resid[idx];
      }
}

// ======== attention kernel A: heads-denominator -> Rg[b][p][q] = 1/sum_h exp ========
// Grid 512 (2 blocks/CU), 768 thr = 12 waves = 12 heads. Block covers 64 p x 512 q.
// Per 64-q tile: each wave computes S^T + exp in registers and atomicAdds its e
// directly into Dsh (native ds_add_f32) -- no E staging, no pack/unpack.
// Dsh stride 67 f32 -> atomic bank spread 3*l15 (coprime), ~2-way.
__global__ __launch_bounds__(768) void denom_k(const u16* __restrict__ Q,
                                               const u16* __restrict__ Km,
                                               float* __restrict__ Rg) {
  int xg = blockIdx.x & 7, r = blockIdx.x >> 3;
  int g = xg + 8 * (r & 1);   // 0..15 = (b, qq)
  int pt = r >> 1;            // 0..31
  int b = g >> 2, qq = g & 3;
  int w = threadIdx.x >> 6, lane = threadIdx.x & 63, l15 = lane & 15, quad = lane >> 4;
  __shared__ float Dsh[64][67];  // 17152 B

  for (int i = threadIdx.x; i < 64 * 67; i += 768) (&Dsh[0][0])[i] = 0.f;
  __syncthreads();

  const u16* Qp = Q + ((size_t)(b * H_ + w) * P_ + pt * 64) * HD_;
  const u16* Kbase = Km + ((size_t)(b * H_ + w) * P_ + qq * 512) * HD_;

  bf8 qf[4][2];
  #pragma unroll
  for (int nt = 0; nt < 4; ++nt)
    #pragma unroll
    for (int ks = 0; ks < 2; ++ks)
      qf[nt][ks] = *reinterpret_cast<const bf8*>(Qp + (size_t)(nt * 16 + l15) * HD_ + ks * 32 + quad * 8);

  for (int t = 0; t < 8; ++t) {
    const u16* Kp = Kbase + (size_t)t * 64 * HD_;
    #pragma unroll
    for (int mt = 0; mt < 4; ++mt) {
      bf8 kfa = *reinterpret_cast<const bf8*>(Kp + (size_t)(mt * 16 + l15) * HD_ + quad * 8);
      bf8 kfb = *reinterpret_cast<const bf8*>(Kp + (size_t)(mt * 16 + l15) * HD_ + 32 + quad * 8);
      f4 s[4];
      #pragma unroll
      for (int nt = 0; nt < 4; ++nt) s[nt] = f4{0.f, 0.f, 0.f, 0.f};
      __builtin_amdgcn_s_setprio(1);
      #pragma unroll
      for (int nt = 0; nt < 4; ++nt) {
        s[nt] = mfma16(kfa, qf[nt][0], s[nt]);
        s[nt] = mfma16(kfb, qf[nt][1], s[nt]);
      }
      __builtin_amdgcn_s_setprio(0);
      #pragma unroll
      for (int nt = 0; nt < 4; ++nt) {
        #pragma unroll
        for (int rr = 0; rr < 4; ++rr) {
          float e = __builtin_amdgcn_exp2f(s[nt][rr] * EXPC_);
          atomicAdd(&Dsh[nt * 16 + l15][mt * 16 + quad * 4 + rr], e);
        }
      }
    }
    __syncthreads();  // all heads' adds done
    float* Rw = Rg + ((size_t)(b * P_ + pt * 64)) * P_ + qq * 512 + t * 64;
    for (int c = threadIdx.x; c < 1024; c += 768) {
      int p = c >> 4, qc = (c & 15) * 4;
      f4 rc;
      #pragma unroll
      for (int i = 0; i < 4; ++i) {
        rc[i] = __builtin_amdgcn_rcpf(Dsh[p][qc + i]);
        Dsh[p][qc + i] = 0.f;
      }
      *reinterpret_cast<f4*>(Rw + (size_t)p * P_ + qc) = rc;
    }
    __syncthreads();  // Dsh re-zeroed before next tile's adds
  }
}

// ======== attention kernel B: per-head PV, zero barriers in main loop ========
// Grid 1536, 256 thr = 4 waves; wave = one head, 32 p-rows. Each wave: recompute
// S (MFMA ~free), exp, stage E in its OWN LDS slice (no cross-wave use -> program
// order suffices, NO barriers), multiply by Rg (global, L3-resident), PV-MFMA.
// ~17 KB LDS + ~96 VGPR + 32 AGPR -> up to 4 independent blocks/CU.
__global__ __launch_bounds__(256) void pv_k(const u16* __restrict__ Q,
                                            const u16* __restrict__ Km,
                                            const u16* __restrict__ Vt,
                                            const float* __restrict__ Rg,
                                            u16* __restrict__ O0,
                                            u16* __restrict__ O1) {
  __shared__ __align__(16) u16 smem[4 * 32 * 68];  // 4 wave-slices E[32][68], 17408 B
  int xg = blockIdx.x & 7, r = blockIdx.x >> 3;  // xg = (b,qs)
  int b = xg >> 1, qs = xg & 1;
  int hg = r % 3, pt = r / 3;  // pt 0..63 (32-row tiles)
  int w = threadIdx.x >> 6, lane = threadIdx.x & 63, l15 = lane & 15, quad = lane >> 4;
  int h = hg * 4 + w;
  u16* Ew = smem + w * 32 * 68;

  const u16* Qp = Q + ((size_t)(b * H_ + h) * P_ + pt * 32) * HD_;
  const u16* Kbase = Km + ((size_t)(b * H_ + h) * P_ + qs * 1024) * HD_;
  const u16* Vbase = Vt + (size_t)(b * H_ + h) * HD_ * P_ + qs * 1024;
  const float* Rbase = Rg + ((size_t)(b * P_ + pt * 32)) * P_ + qs * 1024;

  bf8 qf[2][2];
  #pragma unroll
  for (int nt = 0; nt < 2; ++nt)
    #pragma unroll
    for (int ks = 0; ks < 2; ++ks)
      qf[nt][ks] = *reinterpret_cast<const bf8*>(Qp + (size_t)(nt * 16 + l15) * HD_ + ks * 32 + quad * 8);

  f4 oacc[4][2];  // d (4x16) x p (2x16)
  #pragma unroll
  for (int i = 0; i < 4; ++i)
    #pragma unroll
    for (int j = 0; j < 2; ++j) oacc[i][j] = f4{0.f, 0.f, 0.f, 0.f};

  for (int t = 0; t < 16; ++t) {
    const u16* Kp = Kbase + (size_t)t * 64 * HD_;
    // S phase: 64 q in 4 mt-groups; kf loaded in pairs to bound registers
    #pragma unroll
    for (int mth = 0; mth < 2; ++mth) {
      bf8 kf[2][2];
      #pragma unroll
      for (int i = 0; i < 2; ++i)
        #pragma unroll
        for (int ks = 0; ks < 2; ++ks)
          kf[i][ks] = *reinterpret_cast<const bf8*>(
              Kp + (size_t)((mth * 2 + i) * 16 + l15) * HD_ + ks * 32 + quad * 8);
      #pragma unroll
      for (int i = 0; i < 2; ++i) {
        int mt = mth * 2 + i;
        f4 s[2];
        #pragma unroll
        for (int nt = 0; nt < 2; ++nt) s[nt] = f4{0.f, 0.f, 0.f, 0.f};
        __builtin_amdgcn_s_setprio(1);
        #pragma unroll
        for (int nt = 0; nt < 2; ++nt) {
          s[nt] = mfma16(kf[i][0], qf[nt][0], s[nt]);
          s[nt] = mfma16(kf[i][1], qf[nt][1], s[nt]);
        }
        __builtin_amdgcn_s_setprio(0);
        #pragma unroll
        for (int nt = 0; nt < 2; ++nt) {
          f4 e;
          #pragma unroll
          for (int rr = 0; rr < 4; ++rr) e[rr] = __builtin_amdgcn_exp2f(s[nt][rr] * EXPC_);
          *reinterpret_cast<uint2*>(&Ew[(nt * 16 + l15) * 68 + mt * 16 + quad * 4]) = pack4(e);
        }
      }
    }
    // PV: two 32-q halves; E read back (same wave -> program order, no barrier)
    #pragma unroll
    for (int half = 0; half < 2; ++half) {
      int bq = t * 64 + half * 32;
      bf8 vf[4];
      #pragma unroll
      for (int dt = 0; dt < 4; ++dt)
        vf[dt] = *reinterpret_cast<const bf8*>(Vbase + (size_t)(dt * 16 + l15) * P_ + bq + quad * 8);
      #pragma unroll
      for (int pi = 0; pi < 2; ++pi) {
        int pp = pi * 16 + l15;
        uint2 e0 = *reinterpret_cast<const uint2*>(&Ew[pp * 68 + half * 32 + quad * 8]);
        uint2 e1 = *reinterpret_cast<const uint2*>(&Ew[pp * 68 + half * 32 + quad * 8 + 4]);
        const float* Rr = Rbase + (size_t)pp * P_ + bq + quad * 8;
        f4 r0 = *reinterpret_cast<const f4*>(Rr);
        f4 r1 = *reinterpret_cast<const f4*>(Rr + 4);
        bf8 af = mkbf8(unp2(e0) * r0, unp2(e1) * r1);
        __builtin_amdgcn_s_setprio(1);
        #pragma unroll
        for (int dt = 0; dt < 4; ++dt)
          oacc[dt][pi] = mfma16(vf[dt], af, oacc[dt][pi]);
        __builtin_amdgcn_s_setprio(0);
      }
    }
  }
  // epilogue: stage O through LDS (alias smem as [32][4][68]) for coalesced writes
  __syncthreads();
  #pragma unroll
  for (int dt = 0; dt < 4; ++dt)
    #pragma unroll
    for (int pi = 0; pi < 2; ++pi)
      *reinterpret_cast<uint2*>(&smem[(pi * 16 + l15) * 272 + w * 68 + dt * 16 + quad * 4]) =
          pack4(oacc[dt][pi]);
  __syncthreads();
  u16* Op = qs ? O1 : O0;
  #pragma unroll
  for (int j = 0; j < 8; ++j) {
    int c = threadIdx.x + j * 256;  // 0..2047 uint2-chunks
    int p = c >> 6, cw = c & 63;
    int hp = cw >> 4, dq = (cw & 15) * 4;
    uint2 val = *reinterpret_cast<const uint2*>(&smem[p * 272 + hp * 68 + dq]);
    size_t row = (size_t)b * P_ + pt * 32 + p;
    *reinterpret_cast<uint2*>(Op + row * D_ + hg * 256 + hp * 64 + dq) = val;
  }
}

extern "C" void kernel_launch(void* const* d_in, const int* in_sizes, int n_in,
                              void* d_out, int out_size, void* d_ws, size_t ws_size,
                              hipStream_t stream) {
  const float* x = (const float*)d_in[0];
  const float* ln1w = (const float*)d_in[1];
  const float* ln1b = (const float*)d_in[2];
  const float* wqkv = (const float*)d_in[3];
  const float* bqkv = (const float*)d_in[4];
  const float* ln2w = (const float*)d_in[5];
  const float* ln2b = (const float*)d_in[6];
  const float* wfc1 = (const float*)d_in[7];
  const float* bfc1 = (const float*)d_in[8];
  const float* wfc2 = (const float*)d_in[9];
  const float* bfc2 = (const float*)d_in[10];
  float* out = (float*)d_out;

  char* ws = (char*)d_ws;
  size_t off = 0;
  auto alloc = [&](size_t bytes) -> void* {
    void* p = ws + off;
    off += (bytes + 255) & ~(size_t)255;
    return p;
  };
  u16* hln = (u16*)alloc((size_t)8192 * 768 * 2);
  u16* wqkvT = (u16*)alloc((size_t)2304 * 768 * 2);
  u16* wfc1T = (u16*)alloc((size_t)3072 * 768 * 2);
  u16* wfc2T = (u16*)alloc((size_t)768 * 3072 * 2);
  u16* Qb = (u16*)alloc((size_t)B_ * H_ * P_ * HD_ * 2);
  u16* Kb = (u16*)alloc((size_t)B_ * H_ * P_ * HD_ * 2);
  u16* Vtb = (u16*)alloc((size_t)B_ * H_ * HD_ * P_ * 2);
  float* x2 = (float*)alloc((size_t)8192 * 768 * 4);
  u16* O0 = (u16*)alloc((size_t)8192 * 768 * 2);
  u16* O1 = (u16*)alloc((size_t)8192 * 768 * 2);
  u16* gbuf = (u16*)alloc((size_t)8192 * 3072 * 2);
  float* Rg = (float*)alloc((size_t)B_ * P_ * P_ * 4);  // 67 MB reciprocal denoms

  tcast_k<<<dim3(72, 24), 256, 0, stream>>>(wqkv, wqkvT, 768, 2304);
  tcast_k<<<dim3(96, 24), 256, 0, stream>>>(wfc1, wfc1T, 768, 3072);
  tcast_k<<<dim3(24, 96), 256, 0, stream>>>(wfc2, wfc2T, 3072, 768);
  ln_k<<<8192, 256, 0, stream>>>(x, ln1w, ln1b, hln);
  gemm_qkv_k<<<dim3(18, 64), 256, 0, stream>>>(hln, wqkvT, bqkv, Qb, Kb, Vtb);
  denom_k<<<512, 768, 0, stream>>>(Qb, Kb, Rg);
  pv_k<<<1536, 256, 0, stream>>>(Qb, Kb, Vtb, Rg, O0, O1);
  ln2add_k<<<8192, 256, 0, stream>>>(x, O0, O1, ln2w, ln2b, x2, hln);
  gemm_fc1_k<<<dim3(24, 64), 256, 0, stream>>>(hln, wfc1T, bfc1, gbuf);
  gemm_fc2_k<<<dim3(12, 64), 256, 0, stream>>>(gbuf, wfc2T, bfc2, x2, out);
}

// Round 9
// 725.185 us; speedup vs baseline: 2.2188x; 2.2188x over previous
//
#include <hip/hip_runtime.h>
#include <hip/hip_bf16.h>

typedef __bf16 bf8 __attribute__((ext_vector_type(8)));
typedef float f4 __attribute__((ext_vector_type(4)));
typedef unsigned short u16;
typedef unsigned int u32;

#define B_ 4
#define P_ 2048
#define D_ 768
#define H_ 12
#define HD_ 64
// scale * log2(e): exp(s*0.125) = exp2(s * 0.18033688)
#define EXPC_ 0.18033688011112042f

typedef const __attribute__((address_space(1))) void gvoid;
typedef __attribute__((address_space(3))) void lvoid;

__device__ __forceinline__ void gl_lds16(const u16* g, u16* l) {
  __builtin_amdgcn_global_load_lds((gvoid*)g, (lvoid*)l, 16, 0, 0);
}

__device__ __forceinline__ u16 f2bf(float f) {  // RNE
  union { float f; u32 u; } c; c.f = f;
  u32 u = c.u;
  u += 0x7fffu + ((u >> 16) & 1u);
  return (u16)(u >> 16);
}

__device__ __forceinline__ float bf2f(u16 v) {
  union { u32 u; float f; } c; c.u = (u32)v << 16; return c.f;
}

__device__ __forceinline__ uint2 pack4(f4 v) {  // truncating 4xf32 -> 4xbf16
  union { float f; u32 u; } a, b, c, d;
  a.f = v[0]; b.f = v[1]; c.f = v[2]; d.f = v[3];
  uint2 r;
  r.x = (a.u >> 16) | (b.u & 0xffff0000u);
  r.y = (c.u >> 16) | (d.u & 0xffff0000u);
  return r;
}

__device__ __forceinline__ f4 unpack4(ushort4 v) {
  f4 r;
  r[0] = bf2f(v.x); r[1] = bf2f(v.y); r[2] = bf2f(v.z); r[3] = bf2f(v.w);
  return r;
}

__device__ __forceinline__ f4 unp2(uint2 u) {
  f4 r;
  r[0] = bf2f((u16)(u.x & 0xffffu)); r[1] = bf2f((u16)(u.x >> 16));
  r[2] = bf2f((u16)(u.y & 0xffffu)); r[3] = bf2f((u16)(u.y >> 16));
  return r;
}

__device__ __forceinline__ bf8 mkbf8(f4 a, f4 b) {
  union { uint4 u; bf8 v; } c;
  uint2 l = pack4(a), h = pack4(b);
  c.u = make_uint4(l.x, l.y, h.x, h.y);
  return c.v;
}

__device__ __forceinline__ f4 mfma16(bf8 a, bf8 b, f4 c) {
  return __builtin_amdgcn_mfma_f32_16x16x32_bf16(a, b, c, 0, 0, 0);
}

#define ZERO44(acc)                    \
  {                                    \
    f4 z_ = {0.f, 0.f, 0.f, 0.f};      \
    for (int i_ = 0; i_ < 4; ++i_)     \
      for (int j_ = 0; j_ < 4; ++j_)   \
        acc[i_][j_] = z_;              \
  }

// XCD-bijective swizzle for grids with nwg % 8 == 0 (m157).
__device__ __forceinline__ int xcd_swz(int lin, int nwg) {
  return (lin & 7) * (nwg >> 3) + (lin >> 3);
}

// ---------------- transpose-cast fp32 (R,C) -> bf16 (C,R) ----------------
__global__ __launch_bounds__(256) void tcast_k(const float* __restrict__ src,
                                               u16* __restrict__ dst, int R, int C) {
  __shared__ float t[32][33];
  int c0 = blockIdx.x * 32, r0 = blockIdx.y * 32;
  int tx = threadIdx.x & 31, ty = threadIdx.x >> 5;
  #pragma unroll
  for (int i = 0; i < 32; i += 8) {
    int r = r0 + ty + i, c = c0 + tx;
    t[ty + i][tx] = (r < R && c < C) ? src[(size_t)r * C + c] : 0.f;
  }
  __syncthreads();
  #pragma unroll
  for (int i = 0; i < 32; i += 8) {
    int c = c0 + ty + i, r = r0 + tx;
    if (c < C && r < R) dst[(size_t)c * R + r] = f2bf(t[tx][ty + i]);
  }
}

// ---------------- layernorm fp32 -> bf16 (LN1) ----------------
__global__ __launch_bounds__(256) void ln_k(const float* __restrict__ x,
                                            const float* __restrict__ g,
                                            const float* __restrict__ b,
                                            u16* __restrict__ out) {
  int row = blockIdx.x;
  const float* xr = x + (size_t)row * D_;
  float v0 = xr[threadIdx.x], v1 = xr[threadIdx.x + 256], v2 = xr[threadIdx.x + 512];
  float s = v0 + v1 + v2;
  float s2 = v0 * v0 + v1 * v1 + v2 * v2;
  #pragma unroll
  for (int o = 32; o > 0; o >>= 1) {
    s += __shfl_down(s, o, 64);
    s2 += __shfl_down(s2, o, 64);
  }
  __shared__ float a[4], a2[4];
  int wv = threadIdx.x >> 6;
  if ((threadIdx.x & 63) == 0) { a[wv] = s; a2[wv] = s2; }
  __syncthreads();
  s = a[0] + a[1] + a[2] + a[3];
  s2 = a2[0] + a2[1] + a2[2] + a2[3];
  float mean = s * (1.f / 768.f);
  float var = s2 * (1.f / 768.f) - mean * mean;
  float rstd = rsqrtf(var + 1e-5f);
  u16* orow = out + (size_t)row * D_;
  float vv[3] = {v0, v1, v2};
  #pragma unroll
  for (int j = 0; j < 3; ++j) {
    int i = threadIdx.x + j * 256;
    orow[i] = f2bf((vv[j] - mean) * rstd * g[i] + b[i]);
  }
}

// ---------------- x2 = x + O0 + O1; hln = LN(x2) ----------------
__global__ __launch_bounds__(256) void ln2add_k(const float* __restrict__ x,
                                                const u16* __restrict__ O0,
                                                const u16* __restrict__ O1,
                                                const float* __restrict__ g,
                                                const float* __restrict__ b,
                                                float* __restrict__ x2,
                                                u16* __restrict__ out) {
  int row = blockIdx.x;
  const float* xr = x + (size_t)row * D_;
  const u16* o0 = O0 + (size_t)row * D_;
  const u16* o1 = O1 + (size_t)row * D_;
  float vv[3];
  #pragma unroll
  for (int j = 0; j < 3; ++j) {
    int i = threadIdx.x + j * 256;
    vv[j] = xr[i] + bf2f(o0[i]) + bf2f(o1[i]);
  }
  float s = vv[0] + vv[1] + vv[2];
  float s2 = vv[0] * vv[0] + vv[1] * vv[1] + vv[2] * vv[2];
  #pragma unroll
  for (int o = 32; o > 0; o >>= 1) {
    s += __shfl_down(s, o, 64);
    s2 += __shfl_down(s2, o, 64);
  }
  __shared__ float a[4], a2[4];
  int wv = threadIdx.x >> 6;
  if ((threadIdx.x & 63) == 0) { a[wv] = s; a2[wv] = s2; }
  __syncthreads();
  s = a[0] + a[1] + a[2] + a[3];
  s2 = a2[0] + a2[1] + a2[2] + a2[3];
  float mean = s * (1.f / 768.f);
  float var = s2 * (1.f / 768.f) - mean * mean;
  float rstd = rsqrtf(var + 1e-5f);
  float* x2r = x2 + (size_t)row * D_;
  u16* orow = out + (size_t)row * D_;
  #pragma unroll
  for (int j = 0; j < 3; ++j) {
    int i = threadIdx.x + j * 256;
    x2r[i] = vv[j];
    orow[i] = f2bf((vv[j] - mean) * rstd * g[i] + b[i]);
  }
}

// ============ staged 128x128 GEMM core (m97 pattern), K-stride 32 ============
template <int K>
__device__ __forceinline__ void staged_core(const u16* __restrict__ Ab,
                                            const u16* __restrict__ Bb,
                                            u16* As, u16* Bs, f4 acc[4][4]) {
  const int wave = threadIdx.x >> 6, lane = threadIdx.x & 63;
  const int l15 = lane & 15, quad = lane >> 4;
  const int lrow = lane >> 2;
  const int lcol = (lane & 3) * 8;
  const int mw = (wave & 1) * 64, nw = (wave >> 1) * 64;
  for (int k0 = 0; k0 < K; k0 += 32) {
    const u16* ga = Ab + (size_t)(wave * 32 + lrow) * K + k0 + lcol;
    gl_lds16(ga, &As[(wave * 32) * 32]);
    gl_lds16(ga + (size_t)16 * K, &As[(wave * 32 + 16) * 32]);
    const u16* gb = Bb + (size_t)(wave * 32 + lrow) * K + k0 + lcol;
    gl_lds16(gb, &Bs[(wave * 32) * 32]);
    gl_lds16(gb + (size_t)16 * K, &Bs[(wave * 32 + 16) * 32]);
    __syncthreads();
    bf8 a[4], b[4];
    #pragma unroll
    for (int mt = 0; mt < 4; ++mt)
      a[mt] = *reinterpret_cast<const bf8*>(&As[(mw + mt * 16 + l15) * 32 + quad * 8]);
    #pragma unroll
    for (int nt = 0; nt < 4; ++nt)
      b[nt] = *reinterpret_cast<const bf8*>(&Bs[(nw + nt * 16 + l15) * 32 + quad * 8]);
    __builtin_amdgcn_s_setprio(1);
    #pragma unroll
    for (int mt = 0; mt < 4; ++mt)
      #pragma unroll
      for (int nt = 0; nt < 4; ++nt)
        acc[mt][nt] = mfma16(a[mt], b[nt], acc[mt][nt]);
    __builtin_amdgcn_s_setprio(0);
    __syncthreads();
  }
}

// ---------------- QKV GEMM staged ----------------
__global__ __launch_bounds__(256) void gemm_qkv_k(const u16* __restrict__ hln,
                                                  const u16* __restrict__ wT,
                                                  const float* __restrict__ bias,
                                                  u16* __restrict__ Q, u16* __restrict__ Km,
                                                  u16* __restrict__ Vt) {
  __shared__ u16 As[128 * 32], Bs[128 * 32];
  int lin = blockIdx.y * gridDim.x + blockIdx.x;
  int swz = xcd_swz(lin, gridDim.x * gridDim.y);
  int m0 = (swz / gridDim.x) * 128, n0 = (swz % gridDim.x) * 128;
  f4 acc[4][4];
  ZERO44(acc);
  staged_core<768>(hln + (size_t)m0 * 768, wT + (size_t)n0 * 768, As, Bs, acc);
  int wave = threadIdx.x >> 6, lane = threadIdx.x & 63, l15 = lane & 15, quad = lane >> 4;
  int mW = m0 + (wave & 1) * 64, nW = n0 + (wave >> 1) * 64;
  #pragma unroll
  for (int mt = 0; mt < 4; ++mt)
    #pragma unroll
    for (int nt = 0; nt < 4; ++nt)
      #pragma unroll
      for (int r = 0; r < 4; ++r) {
        int m = mW + mt * 16 + quad * 4 + r;
        int n = nW + nt * 16 + l15;
        float v = acc[mt][nt][r] + bias[n];
        u16 bv = f2bf(v);
        int b = m >> 11, p = m & 2047;
        int which = n / 768, hn = n % 768;
        int h = hn >> 6, d = hn & 63;
        if (which == 0)
          Q[((size_t)(b * H_ + h) * P_ + p) * HD_ + d] = bv;
        else if (which == 1)
          Km[((size_t)(b * H_ + h) * P_ + p) * HD_ + d] = bv;
        else
          Vt[((size_t)(b * H_ + h) * HD_ + d) * P_ + p] = bv;
      }
}

// ---------------- FC1 GEMM staged + exact GELU ----------------
__global__ __launch_bounds__(256) void gemm_fc1_k(const u16* __restrict__ A,
                                                  const u16* __restrict__ wT,
                                                  const float* __restrict__ bias,
                                                  u16* __restrict__ out) {
  __shared__ u16 As[128 * 32], Bs[128 * 32];
  int lin = blockIdx.y * gridDim.x + blockIdx.x;
  int swz = xcd_swz(lin, gridDim.x * gridDim.y);
  int m0 = (swz / gridDim.x) * 128, n0 = (swz % gridDim.x) * 128;
  f4 acc[4][4];
  ZERO44(acc);
  staged_core<768>(A + (size_t)m0 * 768, wT + (size_t)n0 * 768, As, Bs, acc);
  int wave = threadIdx.x >> 6, lane = threadIdx.x & 63, l15 = lane & 15, quad = lane >> 4;
  int mW = m0 + (wave & 1) * 64, nW = n0 + (wave >> 1) * 64;
  #pragma unroll
  for (int mt = 0; mt < 4; ++mt)
    #pragma unroll
    for (int nt = 0; nt < 4; ++nt)
      #pragma unroll
      for (int r = 0; r < 4; ++r) {
        int m = mW + mt * 16 + quad * 4 + r;
        int n = nW + nt * 16 + l15;
        float v = acc[mt][nt][r] + bias[n];
        v = 0.5f * v * (1.f + erff(v * 0.70710678f));
        out[(size_t)m * 3072 + n] = f2bf(v);
      }
}

// ---------------- FC2 GEMM staged (BM=128, BN=64), +bias +residual -> fp32 ----------------
__global__ __launch_bounds__(256) void gemm_fc2_k(const u16* __restrict__ A,
                                                  const u16* __restrict__ wT,
                                                  const float* __restrict__ bias,
                                                  const float* __restrict__ resid,
                                                  float* __restrict__ out) {
  __shared__ u16 As[128 * 32], Bs[64 * 32];
  int wave = threadIdx.x >> 6, lane = threadIdx.x & 63, l15 = lane & 15, quad = lane >> 4;
  int lrow = lane >> 2, lcol = (lane & 3) * 8;
  int lin = blockIdx.y * gridDim.x + blockIdx.x;
  int swz = xcd_swz(lin, gridDim.x * gridDim.y);
  int m0 = (swz / gridDim.x) * 128, n0 = (swz % gridDim.x) * 64;
  const u16* Ab = A + (size_t)m0 * 3072;
  const u16* Bb = wT + (size_t)n0 * 3072;
  int mw = (wave & 1) * 64, nw = (wave >> 1) * 32;
  f4 acc[4][2];
  #pragma unroll
  for (int i = 0; i < 4; ++i)
    #pragma unroll
    for (int j = 0; j < 2; ++j) acc[i][j] = f4{0.f, 0.f, 0.f, 0.f};
  for (int k0 = 0; k0 < 3072; k0 += 32) {
    const u16* ga = Ab + (size_t)(wave * 32 + lrow) * 3072 + k0 + lcol;
    gl_lds16(ga, &As[(wave * 32) * 32]);
    gl_lds16(ga + (size_t)16 * 3072, &As[(wave * 32 + 16) * 32]);
    const u16* gb = Bb + (size_t)(wave * 16 + lrow) * 3072 + k0 + lcol;
    gl_lds16(gb, &Bs[(wave * 16) * 32]);
    __syncthreads();
    bf8 a[4], b[2];
    #pragma unroll
    for (int mt = 0; mt < 4; ++mt)
      a[mt] = *reinterpret_cast<const bf8*>(&As[(mw + mt * 16 + l15) * 32 + quad * 8]);
    #pragma unroll
    for (int nt = 0; nt < 2; ++nt)
      b[nt] = *reinterpret_cast<const bf8*>(&Bs[(nw + nt * 16 + l15) * 32 + quad * 8]);
    __builtin_amdgcn_s_setprio(1);
    #pragma unroll
    for (int mt = 0; mt < 4; ++mt)
      #pragma unroll
      for (int nt = 0; nt < 2; ++nt)
        acc[mt][nt] = mfma16(a[mt], b[nt], acc[mt][nt]);
    __builtin_amdgcn_s_setprio(0);
    __syncthreads();
  }
  int mW = m0 + mw, nW = n0 + nw;
  #pragma unroll
  for (int mt = 0; mt < 4; ++mt)
    #pragma unroll
    for (int nt = 0; nt < 2; ++nt)
      #pragma unroll
      for (int r = 0; r < 4; ++r) {
        int m = mW + mt * 16 + quad * 4 + r;
        int n = nW + nt * 16 + l15;
        size_t idx = (size_t)m * 768 + n;
        out[idx] = acc[mt][nt][r] + bias[n] + resid[idx];
      }
}

// ======== fused attention v10: heads-softmax in SMALL blocks (4 waves x 3 heads) ========
// Block = 256 thr = 4 waves; covers 16 p-rows x ALL 12 heads x 1024 q (qs half).
// Wave w handles heads {w, w+4, w+8}. LDS 16128 B -> 3-4 INDEPENDENT blocks/CU
// (256-thr blocks co-schedule; 768-thr never did, rounds 0-6). Barrier skew and
// K/V latency now hide across blocks. Grid 1024 = 8 (b,qs -> XCD) x 128 pt;
// per-XCD K+V working set ~3.1 MB < 4 MB L2.
// Per 32-q tile: S^T+exp per head -> E[h] (own-plane, program order); b1;
// R[p][q]=1/sum_h E (128 thr); b2; PV per head (E*R as bf16 A-frag).
// Same 2-barrier hazard protocol as v7.
__global__ __launch_bounds__(256) void attn_k(const u16* __restrict__ Q,
                                              const u16* __restrict__ Km,
                                              const u16* __restrict__ Vt,
                                              u16* __restrict__ O0,
                                              u16* __restrict__ O1) {
  __shared__ __align__(16) u16 E[12][16][36];  // 13824 B, row stride 72 B
  __shared__ __align__(16) float R[16][36];    // 2304 B, row stride 144 B

  int id = blockIdx.x;
  int g = id & 7, pt = id >> 3;  // pt 0..127, 16 p-rows
  int b = g >> 1, qs = g & 1;
  int w = threadIdx.x >> 6, lane = threadIdx.x & 63, l15 = lane & 15, quad = lane >> 4;

  // Q fragments for this wave's 3 heads (16 p-rows each, persist)
  bf8 qf[3][2];
  #pragma unroll
  for (int hi = 0; hi < 3; ++hi) {
    int h = w + 4 * hi;
    const u16* Qp = Q + ((size_t)(b * H_ + h) * P_ + pt * 16) * HD_;
    #pragma unroll
    for (int ks = 0; ks < 2; ++ks)
      qf[hi][ks] = *reinterpret_cast<const bf8*>(Qp + (size_t)l15 * HD_ + ks * 32 + quad * 8);
  }

  f4 oacc[3][4];  // per head: O^T d(4x16) x p(1x16)
  #pragma unroll
  for (int i = 0; i < 3; ++i)
    #pragma unroll
    for (int j = 0; j < 4; ++j) oacc[i][j] = f4{0.f, 0.f, 0.f, 0.f};

  for (int qt = 0; qt < 32; ++qt) {
    // ---- S phase: 3 heads, own E planes (no cross-wave hazard) ----
    #pragma unroll
    for (int hi = 0; hi < 3; ++hi) {
      int h = w + 4 * hi;
      const u16* Kp = Km + ((size_t)(b * H_ + h) * P_ + qs * 1024 + qt * 32) * HD_;
      bf8 kf[2][2];
      #pragma unroll
      for (int mt = 0; mt < 2; ++mt)
        #pragma unroll
        for (int ks = 0; ks < 2; ++ks)
          kf[mt][ks] = *reinterpret_cast<const bf8*>(Kp + (size_t)(mt * 16 + l15) * HD_ + ks * 32 + quad * 8);
      #pragma unroll
      for (int mt = 0; mt < 2; ++mt) {
        f4 s = {0.f, 0.f, 0.f, 0.f};
        __builtin_amdgcn_s_setprio(1);
        s = mfma16(kf[mt][0], qf[hi][0], s);
        s = mfma16(kf[mt][1], qf[hi][1], s);
        __builtin_amdgcn_s_setprio(0);
        f4 e;
        #pragma unroll
        for (int r = 0; r < 4; ++r) e[r] = __builtin_amdgcn_exp2f(s[r] * EXPC_);
        *reinterpret_cast<uint2*>(&E[h][l15][mt * 16 + quad * 4]) = pack4(e);
      }
    }
    __syncthreads();  // b1: all E planes complete
    // ---- R phase: R[p][q] = 1/sum_h E (16p x 32q = 128 f4 chunks) ----
    if (threadIdx.x < 128) {
      int p = threadIdx.x >> 3, qc = (threadIdx.x & 7) * 4;
      f4 sum = {0.f, 0.f, 0.f, 0.f};
      #pragma unroll
      for (int h = 0; h < 12; ++h)
        sum += unpack4(*reinterpret_cast<const ushort4*>(&E[h][p][qc]));
      f4 rc;
      #pragma unroll
      for (int c = 0; c < 4; ++c) rc[c] = __builtin_amdgcn_rcpf(sum[c]);
      *reinterpret_cast<f4*>(&R[p][qc]) = rc;
    }
    __syncthreads();  // b2: R ready
    // ---- PV phase: 3 heads ----
    #pragma unroll
    for (int hi = 0; hi < 3; ++hi) {
      int h = w + 4 * hi;
      const u16* Vp = Vt + (size_t)(b * H_ + h) * HD_ * P_ + qs * 1024 + qt * 32;
      bf8 vf[4];
      #pragma unroll
      for (int dt = 0; dt < 4; ++dt)
        vf[dt] = *reinterpret_cast<const bf8*>(Vp + (size_t)(dt * 16 + l15) * P_ + quad * 8);
      uint2 e0 = *reinterpret_cast<const uint2*>(&E[h][l15][quad * 8]);
      uint2 e1 = *reinterpret_cast<const uint2*>(&E[h][l15][quad * 8 + 4]);
      f4 r0 = *reinterpret_cast<const f4*>(&R[l15][quad * 8]);
      f4 r1 = *reinterpret_cast<const f4*>(&R[l15][quad * 8 + 4]);
      bf8 af = mkbf8(unp2(e0) * r0, unp2(e1) * r1);
      __builtin_amdgcn_s_setprio(1);
      #pragma unroll
      for (int dt = 0; dt < 4; ++dt)
        oacc[hi][dt] = mfma16(vf[dt], af, oacc[hi][dt]);
      __builtin_amdgcn_s_setprio(0);
    }
    // next tile's S overwrites only THIS wave's planes after its own PV reads;
    // other waves' R reads finished before b2 -> safe with 2 barriers.
  }
  __syncthreads();
  // epilogue: stage O (bf16) via LDS (alias E as Os[6][16][72]) in 2 head-phases
  u16(*Os)[16][72] = reinterpret_cast<u16(*)[16][72]>(&E[0][0][0]);
  u16* Op = qs ? O1 : O0;
  #pragma unroll
  for (int hh = 0; hh < 2; ++hh) {
    #pragma unroll
    for (int hi = 0; hi < 3; ++hi) {
      int h = w + 4 * hi;
      if (h >= hh * 6 && h < hh * 6 + 6) {
        int hp = h - hh * 6;
        #pragma unroll
        for (int dt = 0; dt < 4; ++dt)
          *reinterpret_cast<uint2*>(&Os[hp][l15][dt * 16 + quad * 4]) = pack4(oacc[hi][dt]);
      }
    }
    __syncthreads();
    #pragma unroll
    for (int j = 0; j < 3; ++j) {
      int c = threadIdx.x + j * 256;  // 0..767 uint4 chunks (16 rows x 48)
      int p = c / 48, m = c % 48;
      int hp = m >> 3, d = (m & 7) * 8;
      uint4 val = *reinterpret_cast<const uint4*>(&Os[hp][p][d]);
      size_t go = ((size_t)b * P_ + pt * 16 + p) * D_ + (hh * 6 + hp) * 64 + d;
      *reinterpret_cast<uint4*>(Op + go) = val;
    }
    __syncthreads();
  }
}

extern "C" void kernel_launch(void* const* d_in, const int* in_sizes, int n_in,
                              void* d_out, int out_size, void* d_ws, size_t ws_size,
                              hipStream_t stream) {
  const float* x = (const float*)d_in[0];
  const float* ln1w = (const float*)d_in[1];
  const float* ln1b = (const float*)d_in[2];
  const float* wqkv = (const float*)d_in[3];
  const float* bqkv = (const float*)d_in[4];
  const float* ln2w = (const float*)d_in[5];
  const float* ln2b = (const float*)d_in[6];
  const float* wfc1 = (const float*)d_in[7];
  const float* bfc1 = (const float*)d_in[8];
  const float* wfc2 = (const float*)d_in[9];
  const float* bfc2 = (const float*)d_in[10];
  float* out = (float*)d_out;

  char* ws = (char*)d_ws;
  size_t off = 0;
  auto alloc = [&](size_t bytes) -> void* {
    void* p = ws + off;
    off += (bytes + 255) & ~(size_t)255;
    return p;
  };
  u16* hln = (u16*)alloc((size_t)8192 * 768 * 2);
  u16* wqkvT = (u16*)alloc((size_t)2304 * 768 * 2);
  u16* wfc1T = (u16*)alloc((size_t)3072 * 768 * 2);
  u16* wfc2T = (u16*)alloc((size_t)768 * 3072 * 2);
  u16* Qb = (u16*)alloc((size_t)B_ * H_ * P_ * HD_ * 2);
  u16* Kb = (u16*)alloc((size_t)B_ * H_ * P_ * HD_ * 2);
  u16* Vtb = (u16*)alloc((size_t)B_ * H_ * HD_ * P_ * 2);
  float* x2 = (float*)alloc((size_t)8192 * 768 * 4);
  u16* O0 = (u16*)alloc((size_t)8192 * 768 * 2);
  u16* O1 = (u16*)alloc((size_t)8192 * 768 * 2);
  u16* gbuf = (u16*)alloc((size_t)8192 * 3072 * 2);

  tcast_k<<<dim3(72, 24), 256, 0, stream>>>(wqkv, wqkvT, 768, 2304);
  tcast_k<<<dim3(96, 24), 256, 0, stream>>>(wfc1, wfc1T, 768, 3072);
  tcast_k<<<dim3(24, 96), 256, 0, stream>>>(wfc2, wfc2T, 3072, 768);
  ln_k<<<8192, 256, 0, stream>>>(x, ln1w, ln1b, hln);
  gemm_qkv_k<<<dim3(18, 64), 256, 0, stream>>>(hln, wqkvT, bqkv, Qb, Kb, Vtb);
  attn_k<<<1024, 256, 0, stream>>>(Qb, Kb, Vtb, O0, O1);
  ln2add_k<<<8192, 256, 0, stream>>>(x, O0, O1, ln2w, ln2b, x2, hln);
  gemm_fc1_k<<<dim3(24, 64), 256, 0, stream>>>(hln, wfc1T, bfc1, gbuf);
  gemm_fc2_k<<<dim3(12, 64), 256, 0, stream>>>(gbuf, wfc2T, bfc2, x2, out);
}

// Round 10
// 461.552 us; speedup vs baseline: 3.4862x; 1.5712x over previous
//
#include <hip/hip_runtime.h>
#include <hip/hip_bf16.h>

typedef __bf16 bf8 __attribute__((ext_vector_type(8)));
typedef float f4 __attribute__((ext_vector_type(4)));
typedef unsigned short u16;
typedef unsigned int u32;

#define B_ 4
#define P_ 2048
#define D_ 768
#define H_ 12
#define HD_ 64
// scale * log2(e): exp(s*0.125) = exp2(s * 0.18033688)
#define EXPC_ 0.18033688011112042f

typedef const __attribute__((address_space(1))) void gvoid;
typedef __attribute__((address_space(3))) void lvoid;

__device__ __forceinline__ void gl_lds16(const u16* g, u16* l) {
  __builtin_amdgcn_global_load_lds((gvoid*)g, (lvoid*)l, 16, 0, 0);
}

__device__ __forceinline__ u16 f2bf(float f) {  // RNE
  union { float f; u32 u; } c; c.f = f;
  u32 u = c.u;
  u += 0x7fffu + ((u >> 16) & 1u);
  return (u16)(u >> 16);
}

__device__ __forceinline__ float bf2f(u16 v) {
  union { u32 u; float f; } c; c.u = (u32)v << 16; return c.f;
}

__device__ __forceinline__ uint2 pack4(f4 v) {  // truncating 4xf32 -> 4xbf16
  union { float f; u32 u; } a, b, c, d;
  a.f = v[0]; b.f = v[1]; c.f = v[2]; d.f = v[3];
  uint2 r;
  r.x = (a.u >> 16) | (b.u & 0xffff0000u);
  r.y = (c.u >> 16) | (d.u & 0xffff0000u);
  return r;
}

__device__ __forceinline__ f4 unpack4(ushort4 v) {
  f4 r;
  r[0] = bf2f(v.x); r[1] = bf2f(v.y); r[2] = bf2f(v.z); r[3] = bf2f(v.w);
  return r;
}

__device__ __forceinline__ f4 unp2(uint2 u) {
  f4 r;
  r[0] = bf2f((u16)(u.x & 0xffffu)); r[1] = bf2f((u16)(u.x >> 16));
  r[2] = bf2f((u16)(u.y & 0xffffu)); r[3] = bf2f((u16)(u.y >> 16));
  return r;
}

__device__ __forceinline__ bf8 mkbf8(f4 a, f4 b) {
  union { uint4 u; bf8 v; } c;
  uint2 l = pack4(a), h = pack4(b);
  c.u = make_uint4(l.x, l.y, h.x, h.y);
  return c.v;
}

__device__ __forceinline__ f4 mfma16(bf8 a, bf8 b, f4 c) {
  return __builtin_amdgcn_mfma_f32_16x16x32_bf16(a, b, c, 0, 0, 0);
}

#define ZERO44(acc)                    \
  {                                    \
    f4 z_ = {0.f, 0.f, 0.f, 0.f};      \
    for (int i_ = 0; i_ < 4; ++i_)     \
      for (int j_ = 0; j_ < 4; ++j_)   \
        acc[i_][j_] = z_;              \
  }

// XCD-bijective swizzle for grids with nwg % 8 == 0 (m157).
__device__ __forceinline__ int xcd_swz(int lin, int nwg) {
  return (lin & 7) * (nwg >> 3) + (lin >> 3);
}

// ---------------- transpose-cast fp32 (R,C) -> bf16 (C,R) ----------------
__global__ __launch_bounds__(256) void tcast_k(const float* __restrict__ src,
                                               u16* __restrict__ dst, int R, int C) {
  __shared__ float t[32][33];
  int c0 = blockIdx.x * 32, r0 = blockIdx.y * 32;
  int tx = threadIdx.x & 31, ty = threadIdx.x >> 5;
  #pragma unroll
  for (int i = 0; i < 32; i += 8) {
    int r = r0 + ty + i, c = c0 + tx;
    t[ty + i][tx] = (r < R && c < C) ? src[(size_t)r * C + c] : 0.f;
  }
  __syncthreads();
  #pragma unroll
  for (int i = 0; i < 32; i += 8) {
    int c = c0 + ty + i, r = r0 + tx;
    if (c < C && r < R) dst[(size_t)c * R + r] = f2bf(t[tx][ty + i]);
  }
}

// ---------------- layernorm fp32 -> bf16 (LN1) ----------------
__global__ __launch_bounds__(256) void ln_k(const float* __restrict__ x,
                                            const float* __restrict__ g,
                                            const float* __restrict__ b,
                                            u16* __restrict__ out) {
  int row = blockIdx.x;
  const float* xr = x + (size_t)row * D_;
  float v0 = xr[threadIdx.x], v1 = xr[threadIdx.x + 256], v2 = xr[threadIdx.x + 512];
  float s = v0 + v1 + v2;
  float s2 = v0 * v0 + v1 * v1 + v2 * v2;
  #pragma unroll
  for (int o = 32; o > 0; o >>= 1) {
    s += __shfl_down(s, o, 64);
    s2 += __shfl_down(s2, o, 64);
  }
  __shared__ float a[4], a2[4];
  int wv = threadIdx.x >> 6;
  if ((threadIdx.x & 63) == 0) { a[wv] = s; a2[wv] = s2; }
  __syncthreads();
  s = a[0] + a[1] + a[2] + a[3];
  s2 = a2[0] + a2[1] + a2[2] + a2[3];
  float mean = s * (1.f / 768.f);
  float var = s2 * (1.f / 768.f) - mean * mean;
  float rstd = rsqrtf(var + 1e-5f);
  u16* orow = out + (size_t)row * D_;
  float vv[3] = {v0, v1, v2};
  #pragma unroll
  for (int j = 0; j < 3; ++j) {
    int i = threadIdx.x + j * 256;
    orow[i] = f2bf((vv[j] - mean) * rstd * g[i] + b[i]);
  }
}

// ---------------- x2 = x + O0 + O1; hln = LN(x2) ----------------
__global__ __launch_bounds__(256) void ln2add_k(const float* __restrict__ x,
                                                const u16* __restrict__ O0,
                                                const u16* __restrict__ O1,
                                                const float* __restrict__ g,
                                                const float* __restrict__ b,
                                                float* __restrict__ x2,
                                                u16* __restrict__ out) {
  int row = blockIdx.x;
  const float* xr = x + (size_t)row * D_;
  const u16* o0 = O0 + (size_t)row * D_;
  const u16* o1 = O1 + (size_t)row * D_;
  float vv[3];
  #pragma unroll
  for (int j = 0; j < 3; ++j) {
    int i = threadIdx.x + j * 256;
    vv[j] = xr[i] + bf2f(o0[i]) + bf2f(o1[i]);
  }
  float s = vv[0] + vv[1] + vv[2];
  float s2 = vv[0] * vv[0] + vv[1] * vv[1] + vv[2] * vv[2];
  #pragma unroll
  for (int o = 32; o > 0; o >>= 1) {
    s += __shfl_down(s, o, 64);
    s2 += __shfl_down(s2, o, 64);
  }
  __shared__ float a[4], a2[4];
  int wv = threadIdx.x >> 6;
  if ((threadIdx.x & 63) == 0) { a[wv] = s; a2[wv] = s2; }
  __syncthreads();
  s = a[0] + a[1] + a[2] + a[3];
  s2 = a2[0] + a2[1] + a2[2] + a2[3];
  float mean = s * (1.f / 768.f);
  float var = s2 * (1.f / 768.f) - mean * mean;
  float rstd = rsqrtf(var + 1e-5f);
  float* x2r = x2 + (size_t)row * D_;
  u16* orow = out + (size_t)row * D_;
  #pragma unroll
  for (int j = 0; j < 3; ++j) {
    int i = threadIdx.x + j * 256;
    x2r[i] = vv[j];
    orow[i] = f2bf((vv[j] - mean) * rstd * g[i] + b[i]);
  }
}

// ===== staged 128x128 GEMM core, 2-phase double-buffered prefetch (T3-min) =====
// STAGE(t+1) issued BEFORE compute(t): gl_lds flight overlaps MFMA; one barrier
// per K-step (the __syncthreads drain covers vmcnt). As/Bs are 2x buffers.
template <int K>
__device__ __forceinline__ void staged_core(const u16* __restrict__ Ab,
                                            const u16* __restrict__ Bb,
                                            u16* As, u16* Bs, f4 acc[4][4]) {
  const int wave = threadIdx.x >> 6, lane = threadIdx.x & 63;
  const int l15 = lane & 15, quad = lane >> 4;
  const int lrow = lane >> 2;
  const int lcol = (lane & 3) * 8;
  const int mw = (wave & 1) * 64, nw = (wave >> 1) * 64;
#define STAGE_(k0_, buf_)                                                       \
  {                                                                             \
    u16* Ad_ = As + (buf_) * 128 * 32;                                          \
    u16* Bd_ = Bs + (buf_) * 128 * 32;                                          \
    const u16* ga_ = Ab + (size_t)(wave * 32 + lrow) * K + (k0_) + lcol;        \
    gl_lds16(ga_, &Ad_[(wave * 32) * 32]);                                      \
    gl_lds16(ga_ + (size_t)16 * K, &Ad_[(wave * 32 + 16) * 32]);                \
    const u16* gb_ = Bb + (size_t)(wave * 32 + lrow) * K + (k0_) + lcol;        \
    gl_lds16(gb_, &Bd_[(wave * 32) * 32]);                                      \
    gl_lds16(gb_ + (size_t)16 * K, &Bd_[(wave * 32 + 16) * 32]);                \
  }
  STAGE_(0, 0);
  __syncthreads();
  int cur = 0;
  for (int k0 = 0; k0 < K; k0 += 32) {
    if (k0 + 32 < K) STAGE_(k0 + 32, cur ^ 1);  // prefetch next tile
    const u16* Ac = As + cur * 128 * 32;
    const u16* Bc = Bs + cur * 128 * 32;
    bf8 a[4], b[4];
    #pragma unroll
    for (int mt = 0; mt < 4; ++mt)
      a[mt] = *reinterpret_cast<const bf8*>(&Ac[(mw + mt * 16 + l15) * 32 + quad * 8]);
    #pragma unroll
    for (int nt = 0; nt < 4; ++nt)
      b[nt] = *reinterpret_cast<const bf8*>(&Bc[(nw + nt * 16 + l15) * 32 + quad * 8]);
    __builtin_amdgcn_s_setprio(1);
    #pragma unroll
    for (int mt = 0; mt < 4; ++mt)
      #pragma unroll
      for (int nt = 0; nt < 4; ++nt)
        acc[mt][nt] = mfma16(a[mt], b[nt], acc[mt][nt]);
    __builtin_amdgcn_s_setprio(0);
    __syncthreads();  // drains vmcnt (prefetch) + lgkm; cur^1 now ready
    cur ^= 1;
  }
#undef STAGE_
}

// ---------------- QKV GEMM staged ----------------
__global__ __launch_bounds__(256) void gemm_qkv_k(const u16* __restrict__ hln,
                                                  const u16* __restrict__ wT,
                                                  const float* __restrict__ bias,
                                                  u16* __restrict__ Q, u16* __restrict__ Km,
                                                  u16* __restrict__ Vt) {
  __shared__ u16 As[2 * 128 * 32], Bs[2 * 128 * 32];  // 32 KB
  int lin = blockIdx.y * gridDim.x + blockIdx.x;
  int swz = xcd_swz(lin, gridDim.x * gridDim.y);
  int m0 = (swz / gridDim.x) * 128, n0 = (swz % gridDim.x) * 128;
  f4 acc[4][4];
  ZERO44(acc);
  staged_core<768>(hln + (size_t)m0 * 768, wT + (size_t)n0 * 768, As, Bs, acc);
  int wave = threadIdx.x >> 6, lane = threadIdx.x & 63, l15 = lane & 15, quad = lane >> 4;
  int mW = m0 + (wave & 1) * 64, nW = n0 + (wave >> 1) * 64;
  #pragma unroll
  for (int mt = 0; mt < 4; ++mt)
    #pragma unroll
    for (int nt = 0; nt < 4; ++nt)
      #pragma unroll
      for (int r = 0; r < 4; ++r) {
        int m = mW + mt * 16 + quad * 4 + r;
        int n = nW + nt * 16 + l15;
        float v = acc[mt][nt][r] + bias[n];
        u16 bv = f2bf(v);
        int b = m >> 11, p = m & 2047;
        int which = n / 768, hn = n % 768;
        int h = hn >> 6, d = hn & 63;
        if (which == 0)
          Q[((size_t)(b * H_ + h) * P_ + p) * HD_ + d] = bv;
        else if (which == 1)
          Km[((size_t)(b * H_ + h) * P_ + p) * HD_ + d] = bv;
        else
          Vt[((size_t)(b * H_ + h) * HD_ + d) * P_ + p] = bv;
      }
}

// ---------------- FC1 GEMM staged + exact GELU ----------------
__global__ __launch_bounds__(256) void gemm_fc1_k(const u16* __restrict__ A,
                                                  const u16* __restrict__ wT,
                                                  const float* __restrict__ bias,
                                                  u16* __restrict__ out) {
  __shared__ u16 As[2 * 128 * 32], Bs[2 * 128 * 32];  // 32 KB
  int lin = blockIdx.y * gridDim.x + blockIdx.x;
  int swz = xcd_swz(lin, gridDim.x * gridDim.y);
  int m0 = (swz / gridDim.x) * 128, n0 = (swz % gridDim.x) * 128;
  f4 acc[4][4];
  ZERO44(acc);
  staged_core<768>(A + (size_t)m0 * 768, wT + (size_t)n0 * 768, As, Bs, acc);
  int wave = threadIdx.x >> 6, lane = threadIdx.x & 63, l15 = lane & 15, quad = lane >> 4;
  int mW = m0 + (wave & 1) * 64, nW = n0 + (wave >> 1) * 64;
  #pragma unroll
  for (int mt = 0; mt < 4; ++mt)
    #pragma unroll
    for (int nt = 0; nt < 4; ++nt)
      #pragma unroll
      for (int r = 0; r < 4; ++r) {
        int m = mW + mt * 16 + quad * 4 + r;
        int n = nW + nt * 16 + l15;
        float v = acc[mt][nt][r] + bias[n];
        v = 0.5f * v * (1.f + erff(v * 0.70710678f));
        out[(size_t)m * 3072 + n] = f2bf(v);
      }
}

// ------- FC2 GEMM staged (BM=128, BN=64), 2-phase dbuf, +bias +residual -> fp32 -------
__global__ __launch_bounds__(256) void gemm_fc2_k(const u16* __restrict__ A,
                                                  const u16* __restrict__ wT,
                                                  const float* __restrict__ bias,
                                                  const float* __restrict__ resid,
                                                  float* __restrict__ out) {
  __shared__ u16 As[2 * 128 * 32], Bs[2 * 64 * 32];  // 24 KB
  int wave = threadIdx.x >> 6, lane = threadIdx.x & 63, l15 = lane & 15, quad = lane >> 4;
  int lrow = lane >> 2, lcol = (lane & 3) * 8;
  int lin = blockIdx.y * gridDim.x + blockIdx.x;
  int swz = xcd_swz(lin, gridDim.x * gridDim.y);
  int m0 = (swz / gridDim.x) * 128, n0 = (swz % gridDim.x) * 64;
  const u16* Ab = A + (size_t)m0 * 3072;
  const u16* Bb = wT + (size_t)n0 * 3072;
  int mw = (wave & 1) * 64, nw = (wave >> 1) * 32;
  f4 acc[4][2];
  #pragma unroll
  for (int i = 0; i < 4; ++i)
    #pragma unroll
    for (int j = 0; j < 2; ++j) acc[i][j] = f4{0.f, 0.f, 0.f, 0.f};
#define STAGE2_(k0_, buf_)                                                      \
  {                                                                             \
    u16* Ad_ = As + (buf_) * 128 * 32;                                          \
    u16* Bd_ = Bs + (buf_) * 64 * 32;                                           \
    const u16* ga_ = Ab + (size_t)(wave * 32 + lrow) * 3072 + (k0_) + lcol;     \
    gl_lds16(ga_, &Ad_[(wave * 32) * 32]);                                      \
    gl_lds16(ga_ + (size_t)16 * 3072, &Ad_[(wave * 32 + 16) * 32]);             \
    const u16* gb_ = Bb + (size_t)(wave * 16 + lrow) * 3072 + (k0_) + lcol;     \
    gl_lds16(gb_, &Bd_[(wave * 16) * 32]);                                      \
  }
  STAGE2_(0, 0);
  __syncthreads();
  int cur = 0;
  for (int k0 = 0; k0 < 3072; k0 += 32) {
    if (k0 + 32 < 3072) STAGE2_(k0 + 32, cur ^ 1);
    const u16* Ac = As + cur * 128 * 32;
    const u16* Bc = Bs + cur * 64 * 32;
    bf8 a[4], b[2];
    #pragma unroll
    for (int mt = 0; mt < 4; ++mt)
      a[mt] = *reinterpret_cast<const bf8*>(&Ac[(mw + mt * 16 + l15) * 32 + quad * 8]);
    #pragma unroll
    for (int nt = 0; nt < 2; ++nt)
      b[nt] = *reinterpret_cast<const bf8*>(&Bc[(nw + nt * 16 + l15) * 32 + quad * 8]);
    __builtin_amdgcn_s_setprio(1);
    #pragma unroll
    for (int mt = 0; mt < 4; ++mt)
      #pragma unroll
      for (int nt = 0; nt < 2; ++nt)
        acc[mt][nt] = mfma16(a[mt], b[nt], acc[mt][nt]);
    __builtin_amdgcn_s_setprio(0);
    __syncthreads();
    cur ^= 1;
  }
#undef STAGE2_
  int mW = m0 + mw, nW = n0 + nw;
  #pragma unroll
  for (int mt = 0; mt < 4; ++mt)
    #pragma unroll
    for (int nt = 0; nt < 2; ++nt)
      #pragma unroll
      for (int r = 0; r < 4; ++r) {
        int m = mW + mt * 16 + quad * 4 + r;
        int n = nW + nt * 16 + l15;
        size_t idx = (size_t)m * 768 + n;
        out[idx] = acc[mt][nt][r] + bias[n] + resid[idx];
      }
}

// ======== fused attention v7 (proven best, spill-free): heads-softmax, R-pad, setprio ========
// Grid: 256 blocks, 1/CU. g=id&7 -> XCD; (b,qs)=g so each XCD streams ONE (b,qs)
// K/V sequence (L2-resident). 768 threads = 12 waves = 12 heads.
__global__ __launch_bounds__(768) void attn_fused_k(const u16* __restrict__ Q,
                                                    const u16* __restrict__ Km,
                                                    const u16* __restrict__ Vt,
                                                    u16* __restrict__ O0,
                                                    u16* __restrict__ O1) {
  int id = blockIdx.x;
  int g = id & 7, pt = id >> 3;
  int b = g >> 1, qs = g & 1;
  int w = threadIdx.x >> 6, lane = threadIdx.x & 63, l15 = lane & 15, quad = lane >> 4;
  __shared__ __align__(16) u16 E[12][64][36];  // 55296 B, row stride 72 B
  __shared__ __align__(16) float R[64][36];    // 9216 B, row stride 144 B

  const u16* Qp = Q + ((size_t)(b * H_ + w) * P_ + pt * 64) * HD_;
  const u16* Kbase = Km + ((size_t)(b * H_ + w) * P_ + qs * 1024) * HD_;
  const u16* Vbase = Vt + (size_t)(b * H_ + w) * HD_ * P_ + qs * 1024;

  // Q fragments: 64 p-rows of this wave's head (persist across all q-tiles)
  bf8 qf[4][2];
  #pragma unroll
  for (int nt = 0; nt < 4; ++nt)
    #pragma unroll
    for (int ks = 0; ks < 2; ++ks)
      qf[nt][ks] = *reinterpret_cast<const bf8*>(Qp + (size_t)(nt * 16 + l15) * HD_ + ks * 32 + quad * 8);

  f4 oacc[4][4];  // O^T: d (4x16) x p (4x16)
  ZERO44(oacc);

  for (int qt = 0; qt < 32; ++qt) {
    const u16* Kp = Kbase + (size_t)qt * 32 * HD_;
    bf8 kf[2][2];
    #pragma unroll
    for (int mt = 0; mt < 2; ++mt)
      #pragma unroll
      for (int ks = 0; ks < 2; ++ks)
        kf[mt][ks] = *reinterpret_cast<const bf8*>(Kp + (size_t)(mt * 16 + l15) * HD_ + ks * 32 + quad * 8);
    // V fragments issued early (drain during S/exp)
    bf8 vf[4];
    #pragma unroll
    for (int dt = 0; dt < 4; ++dt)
      vf[dt] = *reinterpret_cast<const bf8*>(Vbase + (size_t)(dt * 16 + l15) * P_ + qt * 32 + quad * 8);
    // S^T + exp -> E[w], one mt (16 q-rows) at a time
    #pragma unroll
    for (int mt = 0; mt < 2; ++mt) {
      f4 s[4];
      #pragma unroll
      for (int nt = 0; nt < 4; ++nt) s[nt] = f4{0.f, 0.f, 0.f, 0.f};
      __builtin_amdgcn_s_setprio(1);
      #pragma unroll
      for (int nt = 0; nt < 4; ++nt) {
        s[nt] = mfma16(kf[mt][0], qf[nt][0], s[nt]);
        s[nt] = mfma16(kf[mt][1], qf[nt][1], s[nt]);
      }
      __builtin_amdgcn_s_setprio(0);
      #pragma unroll
      for (int nt = 0; nt < 4; ++nt) {
        f4 e;
        #pragma unroll
        for (int r = 0; r < 4; ++r) e[r] = __builtin_amdgcn_exp2f(s[nt][r] * EXPC_);
        *reinterpret_cast<uint2*>(&E[w][nt * 16 + l15][mt * 16 + quad * 4]) = pack4(e);
      }
    }
    __syncthreads();
    // R[p][q] = 1 / sum_h E[h][p][q]  (512 threads, one f4 chunk each)
    if (threadIdx.x < 512) {
      int p = threadIdx.x >> 3, qc = (threadIdx.x & 7) * 4;
      f4 sum = {0.f, 0.f, 0.f, 0.f};
      #pragma unroll
      for (int h = 0; h < 12; ++h)
        sum += unpack4(*reinterpret_cast<const ushort4*>(&E[h][p][qc]));
      f4 rc;
      #pragma unroll
      for (int c = 0; c < 4; ++c) rc[c] = __builtin_amdgcn_rcpf(sum[c]);
      *reinterpret_cast<f4*>(&R[p][qc]) = rc;
    }
    __syncthreads();
    // O^T += V^T-frag @ (E[w]*R)-frag
    #pragma unroll
    for (int pi = 0; pi < 4; ++pi) {
      int pp = pi * 16 + l15;
      uint2 e0 = *reinterpret_cast<const uint2*>(&E[w][pp][quad * 8]);
      uint2 e1 = *reinterpret_cast<const uint2*>(&E[w][pp][quad * 8 + 4]);
      f4 r0 = *reinterpret_cast<const f4*>(&R[pp][quad * 8]);
      f4 r1 = *reinterpret_cast<const f4*>(&R[pp][quad * 8 + 4]);
      bf8 af = mkbf8(unp2(e0) * r0, unp2(e1) * r1);
      __builtin_amdgcn_s_setprio(1);
      #pragma unroll
      for (int dt = 0; dt < 4; ++dt)
        oacc[dt][pi] = mfma16(vf[dt], af, oacc[dt][pi]);
      __builtin_amdgcn_s_setprio(0);
    }
    // no trailing barrier: E[w] single-writer/reader per wave; R guarded by b1/b2
  }
  __syncthreads();
  // epilogue: stage O^T (bf16) through LDS (alias E as [6][64][72]) in 2 head-phases
  u16(*Os)[64][72] = reinterpret_cast<u16(*)[64][72]>(&E[0][0][0]);
  u16* Op = qs ? O1 : O0;
  #pragma unroll
  for (int hh = 0; hh < 2; ++hh) {
    if (w >= hh * 6 && w < hh * 6 + 6) {
      int wp = w - hh * 6;
      #pragma unroll
      for (int dt = 0; dt < 4; ++dt)
        #pragma unroll
        for (int pi = 0; pi < 4; ++pi)
          *reinterpret_cast<uint2*>(&Os[wp][pi * 16 + l15][dt * 16 + quad * 4]) = pack4(oacc[dt][pi]);
    }
    __syncthreads();
    #pragma unroll
    for (int j = 0; j < 4; ++j) {
      int c = threadIdx.x + j * 768;   // 0..3071
      int p = c / 48, m = c % 48;
      int hp = m >> 3, d = (m & 7) * 8;
      uint4 val = *reinterpret_cast<const uint4*>(&Os[hp][p][d]);
      size_t go = (((size_t)b * P_) + pt * 64 + p) * D_ + (hh * 6 + hp) * 64 + d;
      *reinterpret_cast<uint4*>(Op + go) = val;
    }
    __syncthreads();
  }
}

extern "C" void kernel_launch(void* const* d_in, const int* in_sizes, int n_in,
                              void* d_out, int out_size, void* d_ws, size_t ws_size,
                              hipStream_t stream) {
  const float* x = (const float*)d_in[0];
  const float* ln1w = (const float*)d_in[1];
  const float* ln1b = (const float*)d_in[2];
  const float* wqkv = (const float*)d_in[3];
  const float* bqkv = (const float*)d_in[4];
  const float* ln2w = (const float*)d_in[5];
  const float* ln2b = (const float*)d_in[6];
  const float* wfc1 = (const float*)d_in[7];
  const float* bfc1 = (const float*)d_in[8];
  const float* wfc2 = (const float*)d_in[9];
  const float* bfc2 = (const float*)d_in[10];
  float* out = (float*)d_out;

  char* ws = (char*)d_ws;
  size_t off = 0;
  auto alloc = [&](size_t bytes) -> void* {
    void* p = ws + off;
    off += (bytes + 255) & ~(size_t)255;
    return p;
  };
  u16* hln = (u16*)alloc((size_t)8192 * 768 * 2);
  u16* wqkvT = (u16*)alloc((size_t)2304 * 768 * 2);
  u16* wfc1T = (u16*)alloc((size_t)3072 * 768 * 2);
  u16* wfc2T = (u16*)alloc((size_t)768 * 3072 * 2);
  u16* Qb = (u16*)alloc((size_t)B_ * H_ * P_ * HD_ * 2);
  u16* Kb = (u16*)alloc((size_t)B_ * H_ * P_ * HD_ * 2);
  u16* Vtb = (u16*)alloc((size_t)B_ * H_ * HD_ * P_ * 2);
  float* x2 = (float*)alloc((size_t)8192 * 768 * 4);
  u16* O0 = (u16*)alloc((size_t)8192 * 768 * 2);
  u16* O1 = (u16*)alloc((size_t)8192 * 768 * 2);
  u16* gbuf = (u16*)alloc((size_t)8192 * 3072 * 2);

  tcast_k<<<dim3(72, 24), 256, 0, stream>>>(wqkv, wqkvT, 768, 2304);
  tcast_k<<<dim3(96, 24), 256, 0, stream>>>(wfc1, wfc1T, 768, 3072);
  tcast_k<<<dim3(24, 96), 256, 0, stream>>>(wfc2, wfc2T, 3072, 768);
  ln_k<<<8192, 256, 0, stream>>>(x, ln1w, ln1b, hln);
  gemm_qkv_k<<<dim3(18, 64), 256, 0, stream>>>(hln, wqkvT, bqkv, Qb, Kb, Vtb);
  attn_fused_k<<<256, 768, 0, stream>>>(Qb, Kb, Vtb, O0, O1);
  ln2add_k<<<8192, 256, 0, stream>>>(x, O0, O1, ln2w, ln2b, x2, hln);
  gemm_fc1_k<<<dim3(24, 64), 256, 0, stream>>>(hln, wfc1T, bfc1, gbuf);
  gemm_fc2_k<<<dim3(12, 64), 256, 0, stream>>>(gbuf, wfc2T, bfc2, x2, out);
}

// Round 11
// 444.059 us; speedup vs baseline: 3.6236x; 1.0394x over previous
//
#include <hip/hip_runtime.h>
#include <hip/hip_bf16.h>

typedef __bf16 bf8 __attribute__((ext_vector_type(8)));
typedef float f4 __attribute__((ext_vector_type(4)));
typedef unsigned short u16;
typedef unsigned int u32;

#define B_ 4
#define P_ 2048
#define D_ 768
#define H_ 12
#define HD_ 64
// scale * log2(e): exp(s*0.125) = exp2(s * 0.18033688)
#define EXPC_ 0.18033688011112042f

typedef const __attribute__((address_space(1))) void gvoid;
typedef __attribute__((address_space(3))) void lvoid;

__device__ __forceinline__ void gl_lds16(const u16* g, u16* l) {
  __builtin_amdgcn_global_load_lds((gvoid*)g, (lvoid*)l, 16, 0, 0);
}

__device__ __forceinline__ u16 f2bf(float f) {  // RNE
  union { float f; u32 u; } c; c.f = f;
  u32 u = c.u;
  u += 0x7fffu + ((u >> 16) & 1u);
  return (u16)(u >> 16);
}

__device__ __forceinline__ float bf2f(u16 v) {
  union { u32 u; float f; } c; c.u = (u32)v << 16; return c.f;
}

__device__ __forceinline__ uint2 pack4(f4 v) {  // truncating 4xf32 -> 4xbf16
  union { float f; u32 u; } a, b, c, d;
  a.f = v[0]; b.f = v[1]; c.f = v[2]; d.f = v[3];
  uint2 r;
  r.x = (a.u >> 16) | (b.u & 0xffff0000u);
  r.y = (c.u >> 16) | (d.u & 0xffff0000u);
  return r;
}

__device__ __forceinline__ f4 unpack4(ushort4 v) {
  f4 r;
  r[0] = bf2f(v.x); r[1] = bf2f(v.y); r[2] = bf2f(v.z); r[3] = bf2f(v.w);
  return r;
}

__device__ __forceinline__ f4 unp2(uint2 u) {
  f4 r;
  r[0] = bf2f((u16)(u.x & 0xffffu)); r[1] = bf2f((u16)(u.x >> 16));
  r[2] = bf2f((u16)(u.y & 0xffffu)); r[3] = bf2f((u16)(u.y >> 16));
  return r;
}

__device__ __forceinline__ bf8 mkbf8(f4 a, f4 b) {
  union { uint4 u; bf8 v; } c;
  uint2 l = pack4(a), h = pack4(b);
  c.u = make_uint4(l.x, l.y, h.x, h.y);
  return c.v;
}

__device__ __forceinline__ f4 mfma16(bf8 a, bf8 b, f4 c) {
  return __builtin_amdgcn_mfma_f32_16x16x32_bf16(a, b, c, 0, 0, 0);
}

#define ZERO44(acc)                    \
  {                                    \
    f4 z_ = {0.f, 0.f, 0.f, 0.f};      \
    for (int i_ = 0; i_ < 4; ++i_)     \
      for (int j_ = 0; j_ < 4; ++j_)   \
        acc[i_][j_] = z_;              \
  }

// XCD-bijective swizzle for grids with nwg % 8 == 0 (m157).
__device__ __forceinline__ int xcd_swz(int lin, int nwg) {
  return (lin & 7) * (nwg >> 3) + (lin >> 3);
}

// ======== prep_k: 3 weight transpose-casts + LN1, one launch ========
// Blocks [0,1728): wqkv^T (768x2304); [1728,4032): wfc1^T (768x3072);
// [4032,6336): wfc2^T (3072x768); [6336,14528): LN1 rows 0..8191.
// Merging saves 3 launch gaps and co-fills the machine (all paths independent).
__global__ __launch_bounds__(256) void prep_k(const float* __restrict__ wqkv, u16* __restrict__ wqkvT,
                                              const float* __restrict__ wfc1, u16* __restrict__ wfc1T,
                                              const float* __restrict__ wfc2, u16* __restrict__ wfc2T,
                                              const float* __restrict__ x, const float* __restrict__ g,
                                              const float* __restrict__ b, u16* __restrict__ hln) {
  __shared__ float t[32][33];
  __shared__ float a[4], a2[4];
  int id = blockIdx.x;
  if (id >= 6336) {
    // ---- LN1 path ----
    int row = id - 6336;
    const float* xr = x + (size_t)row * D_;
    float v0 = xr[threadIdx.x], v1 = xr[threadIdx.x + 256], v2 = xr[threadIdx.x + 512];
    float s = v0 + v1 + v2;
    float s2 = v0 * v0 + v1 * v1 + v2 * v2;
    #pragma unroll
    for (int o = 32; o > 0; o >>= 1) {
      s += __shfl_down(s, o, 64);
      s2 += __shfl_down(s2, o, 64);
    }
    int wv = threadIdx.x >> 6;
    if ((threadIdx.x & 63) == 0) { a[wv] = s; a2[wv] = s2; }
    __syncthreads();
    s = a[0] + a[1] + a[2] + a[3];
    s2 = a2[0] + a2[1] + a2[2] + a2[3];
    float mean = s * (1.f / 768.f);
    float var = s2 * (1.f / 768.f) - mean * mean;
    float rstd = rsqrtf(var + 1e-5f);
    u16* orow = hln + (size_t)row * D_;
    float vv[3] = {v0, v1, v2};
    #pragma unroll
    for (int j = 0; j < 3; ++j) {
      int i = threadIdx.x + j * 256;
      orow[i] = f2bf((vv[j] - mean) * rstd * g[i] + b[i]);
    }
    return;
  }
  // ---- transpose-cast path ----
  const float* src;
  u16* dst;
  int R, C, bx, by;
  if (id < 1728) {
    src = wqkv; dst = wqkvT; R = 768; C = 2304; bx = id % 72; by = id / 72;
  } else if (id < 4032) {
    int j = id - 1728;
    src = wfc1; dst = wfc1T; R = 768; C = 3072; bx = j % 96; by = j / 96;
  } else {
    int j = id - 4032;
    src = wfc2; dst = wfc2T; R = 3072; C = 768; bx = j % 24; by = j / 24;
  }
  int c0 = bx * 32, r0 = by * 32;
  int tx = threadIdx.x & 31, ty = threadIdx.x >> 5;
  #pragma unroll
  for (int i = 0; i < 32; i += 8) {
    int r = r0 + ty + i, c = c0 + tx;
    t[ty + i][tx] = (r < R && c < C) ? src[(size_t)r * C + c] : 0.f;
  }
  __syncthreads();
  #pragma unroll
  for (int i = 0; i < 32; i += 8) {
    int c = c0 + ty + i, r = r0 + tx;
    if (c < C && r < R) dst[(size_t)c * R + r] = f2bf(t[tx][ty + i]);
  }
}

// ---------------- x2 = x + O0 + O1; hln = LN(x2) ----------------
__global__ __launch_bounds__(256) void ln2add_k(const float* __restrict__ x,
                                                const u16* __restrict__ O0,
                                                const u16* __restrict__ O1,
                                                const float* __restrict__ g,
                                                const float* __restrict__ b,
                                                float* __restrict__ x2,
                                                u16* __restrict__ out) {
  int row = blockIdx.x;
  const float* xr = x + (size_t)row * D_;
  const u16* o0 = O0 + (size_t)row * D_;
  const u16* o1 = O1 + (size_t)row * D_;
  float vv[3];
  #pragma unroll
  for (int j = 0; j < 3; ++j) {
    int i = threadIdx.x + j * 256;
    vv[j] = xr[i] + bf2f(o0[i]) + bf2f(o1[i]);
  }
  float s = vv[0] + vv[1] + vv[2];
  float s2 = vv[0] * vv[0] + vv[1] * vv[1] + vv[2] * vv[2];
  #pragma unroll
  for (int o = 32; o > 0; o >>= 1) {
    s += __shfl_down(s, o, 64);
    s2 += __shfl_down(s2, o, 64);
  }
  __shared__ float a[4], a2[4];
  int wv = threadIdx.x >> 6;
  if ((threadIdx.x & 63) == 0) { a[wv] = s; a2[wv] = s2; }
  __syncthreads();
  s = a[0] + a[1] + a[2] + a[3];
  s2 = a2[0] + a2[1] + a2[2] + a2[3];
  float mean = s * (1.f / 768.f);
  float var = s2 * (1.f / 768.f) - mean * mean;
  float rstd = rsqrtf(var + 1e-5f);
  float* x2r = x2 + (size_t)row * D_;
  u16* orow = out + (size_t)row * D_;
  #pragma unroll
  for (int j = 0; j < 3; ++j) {
    int i = threadIdx.x + j * 256;
    x2r[i] = vv[j];
    orow[i] = f2bf((vv[j] - mean) * rstd * g[i] + b[i]);
  }
}

// ===== staged 128x128 GEMM core, 2-phase double-buffered prefetch (T3-min) =====
// STAGE(t+1) issued BEFORE compute(t): gl_lds flight overlaps MFMA; one barrier
// per K-step (the __syncthreads drain covers vmcnt). As/Bs are 2x buffers.
template <int K>
__device__ __forceinline__ void staged_core(const u16* __restrict__ Ab,
                                            const u16* __restrict__ Bb,
                                            u16* As, u16* Bs, f4 acc[4][4]) {
  const int wave = threadIdx.x >> 6, lane = threadIdx.x & 63;
  const int l15 = lane & 15, quad = lane >> 4;
  const int lrow = lane >> 2;
  const int lcol = (lane & 3) * 8;
  const int mw = (wave & 1) * 64, nw = (wave >> 1) * 64;
#define STAGE_(k0_, buf_)                                                       \
  {                                                                             \
    u16* Ad_ = As + (buf_) * 128 * 32;                                          \
    u16* Bd_ = Bs + (buf_) * 128 * 32;                                          \
    const u16* ga_ = Ab + (size_t)(wave * 32 + lrow) * K + (k0_) + lcol;        \
    gl_lds16(ga_, &Ad_[(wave * 32) * 32]);                                      \
    gl_lds16(ga_ + (size_t)16 * K, &Ad_[(wave * 32 + 16) * 32]);                \
    const u16* gb_ = Bb + (size_t)(wave * 32 + lrow) * K + (k0_) + lcol;        \
    gl_lds16(gb_, &Bd_[(wave * 32) * 32]);                                      \
    gl_lds16(gb_ + (size_t)16 * K, &Bd_[(wave * 32 + 16) * 32]);                \
  }
  STAGE_(0, 0);
  __syncthreads();
  int cur = 0;
  for (int k0 = 0; k0 < K; k0 += 32) {
    if (k0 + 32 < K) STAGE_(k0 + 32, cur ^ 1);  // prefetch next tile
    const u16* Ac = As + cur * 128 * 32;
    const u16* Bc = Bs + cur * 128 * 32;
    bf8 a[4], b[4];
    #pragma unroll
    for (int mt = 0; mt < 4; ++mt)
      a[mt] = *reinterpret_cast<const bf8*>(&Ac[(mw + mt * 16 + l15) * 32 + quad * 8]);
    #pragma unroll
    for (int nt = 0; nt < 4; ++nt)
      b[nt] = *reinterpret_cast<const bf8*>(&Bc[(nw + nt * 16 + l15) * 32 + quad * 8]);
    __builtin_amdgcn_s_setprio(1);
    #pragma unroll
    for (int mt = 0; mt < 4; ++mt)
      #pragma unroll
      for (int nt = 0; nt < 4; ++nt)
        acc[mt][nt] = mfma16(a[mt], b[nt], acc[mt][nt]);
    __builtin_amdgcn_s_setprio(0);
    __syncthreads();  // drains vmcnt (prefetch) + lgkm; cur^1 now ready
    cur ^= 1;
  }
#undef STAGE_
}

// ---------------- QKV GEMM staged ----------------
__global__ __launch_bounds__(256) void gemm_qkv_k(const u16* __restrict__ hln,
                                                  const u16* __restrict__ wT,
                                                  const float* __restrict__ bias,
                                                  u16* __restrict__ Q, u16* __restrict__ Km,
                                                  u16* __restrict__ Vt) {
  __shared__ u16 As[2 * 128 * 32], Bs[2 * 128 * 32];  // 32 KB
  int lin = blockIdx.y * gridDim.x + blockIdx.x;
  int swz = xcd_swz(lin, gridDim.x * gridDim.y);
  int m0 = (swz / gridDim.x) * 128, n0 = (swz % gridDim.x) * 128;
  f4 acc[4][4];
  ZERO44(acc);
  staged_core<768>(hln + (size_t)m0 * 768, wT + (size_t)n0 * 768, As, Bs, acc);
  int wave = threadIdx.x >> 6, lane = threadIdx.x & 63, l15 = lane & 15, quad = lane >> 4;
  int mW = m0 + (wave & 1) * 64, nW = n0 + (wave >> 1) * 64;
  #pragma unroll
  for (int mt = 0; mt < 4; ++mt)
    #pragma unroll
    for (int nt = 0; nt < 4; ++nt)
      #pragma unroll
      for (int r = 0; r < 4; ++r) {
        int m = mW + mt * 16 + quad * 4 + r;
        int n = nW + nt * 16 + l15;
        float v = acc[mt][nt][r] + bias[n];
        u16 bv = f2bf(v);
        int b = m >> 11, p = m & 2047;
        int which = n / 768, hn = n % 768;
        int h = hn >> 6, d = hn & 63;
        if (which == 0)
          Q[((size_t)(b * H_ + h) * P_ + p) * HD_ + d] = bv;
        else if (which == 1)
          Km[((size_t)(b * H_ + h) * P_ + p) * HD_ + d] = bv;
        else
          Vt[((size_t)(b * H_ + h) * HD_ + d) * P_ + p] = bv;
      }
}

// ---------------- FC1 GEMM staged + fast tanh-GELU ----------------
// erff -> tanh-form GELU via one exp2 (branchless, inf/0-safe):
//   tanh(u) = 1 - 2/(e^{2u}+1);  u = 0.79788456(v + 0.044715 v^3)
//   exponent folded: e = v*(2.3022082 + 0.1029434 v^2)  [2u*log2(e)]
// max dev from exact GELU ~3e-3 << 0.125 tol and < bf16 quantum for |v|>0.8.
__global__ __launch_bounds__(256) void gemm_fc1_k(const u16* __restrict__ A,
                                                  const u16* __restrict__ wT,
                                                  const float* __restrict__ bias,
                                                  u16* __restrict__ out) {
  __shared__ u16 As[2 * 128 * 32], Bs[2 * 128 * 32];  // 32 KB
  int lin = blockIdx.y * gridDim.x + blockIdx.x;
  int swz = xcd_swz(lin, gridDim.x * gridDim.y);
  int m0 = (swz / gridDim.x) * 128, n0 = (swz % gridDim.x) * 128;
  f4 acc[4][4];
  ZERO44(acc);
  staged_core<768>(A + (size_t)m0 * 768, wT + (size_t)n0 * 768, As, Bs, acc);
  int wave = threadIdx.x >> 6, lane = threadIdx.x & 63, l15 = lane & 15, quad = lane >> 4;
  int mW = m0 + (wave & 1) * 64, nW = n0 + (wave >> 1) * 64;
  #pragma unroll
  for (int mt = 0; mt < 4; ++mt)
    #pragma unroll
    for (int nt = 0; nt < 4; ++nt)
      #pragma unroll
      for (int r = 0; r < 4; ++r) {
        int m = mW + mt * 16 + quad * 4 + r;
        int n = nW + nt * 16 + l15;
        float v = acc[mt][nt][r] + bias[n];
        float vv = v * v;
        float e = v * fmaf(0.1029434f, vv, 2.3022082f);
        float tt = __builtin_amdgcn_exp2f(e);
        float th = fmaf(-2.f, __builtin_amdgcn_rcpf(tt + 1.f), 1.f);
        v = 0.5f * v * (1.f + th);
        out[(size_t)m * 3072 + n] = f2bf(v);
      }
}

// ------- FC2 GEMM staged (BM=128, BN=64), 2-phase dbuf, +bias +residual -> fp32 -------
__global__ __launch_bounds__(256) void gemm_fc2_k(const u16* __restrict__ A,
                                                  const u16* __restrict__ wT,
                                                  const float* __restrict__ bias,
                                                  const float* __restrict__ resid,
                                                  float* __restrict__ out) {
  __shared__ u16 As[2 * 128 * 32], Bs[2 * 64 * 32];  // 24 KB
  int wave = threadIdx.x >> 6, lane = threadIdx.x & 63, l15 = lane & 15, quad = lane >> 4;
  int lrow = lane >> 2, lcol = (lane & 3) * 8;
  int lin = blockIdx.y * gridDim.x + blockIdx.x;
  int swz = xcd_swz(lin, gridDim.x * gridDim.y);
  int m0 = (swz / gridDim.x) * 128, n0 = (swz % gridDim.x) * 64;
  const u16* Ab = A + (size_t)m0 * 3072;
  const u16* Bb = wT + (size_t)n0 * 3072;
  int mw = (wave & 1) * 64, nw = (wave >> 1) * 32;
  f4 acc[4][2];
  #pragma unroll
  for (int i = 0; i < 4; ++i)
    #pragma unroll
    for (int j = 0; j < 2; ++j) acc[i][j] = f4{0.f, 0.f, 0.f, 0.f};
#define STAGE2_(k0_, buf_)                                                      \
  {                                                                             \
    u16* Ad_ = As + (buf_) * 128 * 32;                                          \
    u16* Bd_ = Bs + (buf_) * 64 * 32;                                           \
    const u16* ga_ = Ab + (size_t)(wave * 32 + lrow) * 3072 + (k0_) + lcol;     \
    gl_lds16(ga_, &Ad_[(wave * 32) * 32]);                                      \
    gl_lds16(ga_ + (size_t)16 * 3072, &Ad_[(wave * 32 + 16) * 32]);             \
    const u16* gb_ = Bb + (size_t)(wave * 16 + lrow) * 3072 + (k0_) + lcol;     \
    gl_lds16(gb_, &Bd_[(wave * 16) * 32]);                                      \
  }
  STAGE2_(0, 0);
  __syncthreads();
  int cur = 0;
  for (int k0 = 0; k0 < 3072; k0 += 32) {
    if (k0 + 32 < 3072) STAGE2_(k0 + 32, cur ^ 1);
    const u16* Ac = As + cur * 128 * 32;
    const u16* Bc = Bs + cur * 64 * 32;
    bf8 a[4], b[2];
    #pragma unroll
    for (int mt = 0; mt < 4; ++mt)
      a[mt] = *reinterpret_cast<const bf8*>(&Ac[(mw + mt * 16 + l15) * 32 + quad * 8]);
    #pragma unroll
    for (int nt = 0; nt < 2; ++nt)
      b[nt] = *reinterpret_cast<const bf8*>(&Bc[(nw + nt * 16 + l15) * 32 + quad * 8]);
    __builtin_amdgcn_s_setprio(1);
    #pragma unroll
    for (int mt = 0; mt < 4; ++mt)
      #pragma unroll
      for (int nt = 0; nt < 2; ++nt)
        acc[mt][nt] = mfma16(a[mt], b[nt], acc[mt][nt]);
    __builtin_amdgcn_s_setprio(0);
    __syncthreads();
    cur ^= 1;
  }
#undef STAGE2_
  int mW = m0 + mw, nW = n0 + nw;
  #pragma unroll
  for (int mt = 0; mt < 4; ++mt)
    #pragma unroll
    for (int nt = 0; nt < 2; ++nt)
      #pragma unroll
      for (int r = 0; r < 4; ++r) {
        int m = mW + mt * 16 + quad * 4 + r;
        int n = nW + nt * 16 + l15;
        size_t idx = (size_t)m * 768 + n;
        out[idx] = acc[mt][nt][r] + bias[n] + resid[idx];
      }
}

// ======== fused attention v7 (proven best, spill-free): heads-softmax, R-pad, setprio ========
// Grid: 256 blocks, 1/CU. g=id&7 -> XCD; (b,qs)=g so each XCD streams ONE (b,qs)
// K/V sequence (L2-resident). 768 threads = 12 waves = 12 heads.
__global__ __launch_bounds__(768) void attn_fused_k(const u16* __restrict__ Q,
                                                    const u16* __restrict__ Km,
                                                    const u16* __restrict__ Vt,
                                                    u16* __restrict__ O0,
                                                    u16* __restrict__ O1) {
  int id = blockIdx.x;
  int g = id & 7, pt = id >> 3;
  int b = g >> 1, qs = g & 1;
  int w = threadIdx.x >> 6, lane = threadIdx.x & 63, l15 = lane & 15, quad = lane >> 4;
  __shared__ __align__(16) u16 E[12][64][36];  // 55296 B, row stride 72 B
  __shared__ __align__(16) float R[64][36];    // 9216 B, row stride 144 B

  const u16* Qp = Q + ((size_t)(b * H_ + w) * P_ + pt * 64) * HD_;
  const u16* Kbase = Km + ((size_t)(b * H_ + w) * P_ + qs * 1024) * HD_;
  const u16* Vbase = Vt + (size_t)(b * H_ + w) * HD_ * P_ + qs * 1024;

  // Q fragments: 64 p-rows of this wave's head (persist across all q-tiles)
  bf8 qf[4][2];
  #pragma unroll
  for (int nt = 0; nt < 4; ++nt)
    #pragma unroll
    for (int ks = 0; ks < 2; ++ks)
      qf[nt][ks] = *reinterpret_cast<const bf8*>(Qp + (size_t)(nt * 16 + l15) * HD_ + ks * 32 + quad * 8);

  f4 oacc[4][4];  // O^T: d (4x16) x p (4x16)
  ZERO44(oacc);

  for (int qt = 0; qt < 32; ++qt) {
    const u16* Kp = Kbase + (size_t)qt * 32 * HD_;
    bf8 kf[2][2];
    #pragma unroll
    for (int mt = 0; mt < 2; ++mt)
      #pragma unroll
      for (int ks = 0; ks < 2; ++ks)
        kf[mt][ks] = *reinterpret_cast<const bf8*>(Kp + (size_t)(mt * 16 + l15) * HD_ + ks * 32 + quad * 8);
    // V fragments issued early (drain during S/exp)
    bf8 vf[4];
    #pragma unroll
    for (int dt = 0; dt < 4; ++dt)
      vf[dt] = *reinterpret_cast<const bf8*>(Vbase + (size_t)(dt * 16 + l15) * P_ + qt * 32 + quad * 8);
    // S^T + exp -> E[w], one mt (16 q-rows) at a time
    #pragma unroll
    for (int mt = 0; mt < 2; ++mt) {
      f4 s[4];
      #pragma unroll
      for (int nt = 0; nt < 4; ++nt) s[nt] = f4{0.f, 0.f, 0.f, 0.f};
      __builtin_amdgcn_s_setprio(1);
      #pragma unroll
      for (int nt = 0; nt < 4; ++nt) {
        s[nt] = mfma16(kf[mt][0], qf[nt][0], s[nt]);
        s[nt] = mfma16(kf[mt][1], qf[nt][1], s[nt]);
      }
      __builtin_amdgcn_s_setprio(0);
      #pragma unroll
      for (int nt = 0; nt < 4; ++nt) {
        f4 e;
        #pragma unroll
        for (int r = 0; r < 4; ++r) e[r] = __builtin_amdgcn_exp2f(s[nt][r] * EXPC_);
        *reinterpret_cast<uint2*>(&E[w][nt * 16 + l15][mt * 16 + quad * 4]) = pack4(e);
      }
    }
    __syncthreads();
    // R[p][q] = 1 / sum_h E[h][p][q]  (512 threads, one f4 chunk each)
    if (threadIdx.x < 512) {
      int p = threadIdx.x >> 3, qc = (threadIdx.x & 7) * 4;
      f4 sum = {0.f, 0.f, 0.f, 0.f};
      #pragma unroll
      for (int h = 0; h < 12; ++h)
        sum += unpack4(*reinterpret_cast<const ushort4*>(&E[h][p][qc]));
      f4 rc;
      #pragma unroll
      for (int c = 0; c < 4; ++c) rc[c] = __builtin_amdgcn_rcpf(sum[c]);
      *reinterpret_cast<f4*>(&R[p][qc]) = rc;
    }
    __syncthreads();
    // O^T += V^T-frag @ (E[w]*R)-frag
    #pragma unroll
    for (int pi = 0; pi < 4; ++pi) {
      int pp = pi * 16 + l15;
      uint2 e0 = *reinterpret_cast<const uint2*>(&E[w][pp][quad * 8]);
      uint2 e1 = *reinterpret_cast<const uint2*>(&E[w][pp][quad * 8 + 4]);
      f4 r0 = *reinterpret_cast<const f4*>(&R[pp][quad * 8]);
      f4 r1 = *reinterpret_cast<const f4*>(&R[pp][quad * 8 + 4]);
      bf8 af = mkbf8(unp2(e0) * r0, unp2(e1) * r1);
      __builtin_amdgcn_s_setprio(1);
      #pragma unroll
      for (int dt = 0; dt < 4; ++dt)
        oacc[dt][pi] = mfma16(vf[dt], af, oacc[dt][pi]);
      __builtin_amdgcn_s_setprio(0);
    }
    // no trailing barrier: E[w] single-writer/reader per wave; R guarded by b1/b2
  }
  __syncthreads();
  // epilogue: stage O^T (bf16) through LDS (alias E as [6][64][72]) in 2 head-phases
  u16(*Os)[64][72] = reinterpret_cast<u16(*)[64][72]>(&E[0][0][0]);
  u16* Op = qs ? O1 : O0;
  #pragma unroll
  for (int hh = 0; hh < 2; ++hh) {
    if (w >= hh * 6 && w < hh * 6 + 6) {
      int wp = w - hh * 6;
      #pragma unroll
      for (int dt = 0; dt < 4; ++dt)
        #pragma unroll
        for (int pi = 0; pi < 4; ++pi)
          *reinterpret_cast<uint2*>(&Os[wp][pi * 16 + l15][dt * 16 + quad * 4]) = pack4(oacc[dt][pi]);
    }
    __syncthreads();
    #pragma unroll
    for (int j = 0; j < 4; ++j) {
      int c = threadIdx.x + j * 768;   // 0..3071
      int p = c / 48, m = c % 48;
      int hp = m >> 3, d = (m & 7) * 8;
      uint4 val = *reinterpret_cast<const uint4*>(&Os[hp][p][d]);
      size_t go = (((size_t)b * P_) + pt * 64 + p) * D_ + (hh * 6 + hp) * 64 + d;
      *reinterpret_cast<uint4*>(Op + go) = val;
    }
    __syncthreads();
  }
}

extern "C" void kernel_launch(void* const* d_in, const int* in_sizes, int n_in,
                              void* d_out, int out_size, void* d_ws, size_t ws_size,
                              hipStream_t stream) {
  const float* x = (const float*)d_in[0];
  const float* ln1w = (const float*)d_in[1];
  const float* ln1b = (const float*)d_in[2];
  const float* wqkv = (const float*)d_in[3];
  const float* bqkv = (const float*)d_in[4];
  const float* ln2w = (const float*)d_in[5];
  const float* ln2b = (const float*)d_in[6];
  const float* wfc1 = (const float*)d_in[7];
  const float* bfc1 = (const float*)d_in[8];
  const float* wfc2 = (const float*)d_in[9];
  const float* bfc2 = (const float*)d_in[10];
  float* out = (float*)d_out;

  char* ws = (char*)d_ws;
  size_t off = 0;
  auto alloc = [&](size_t bytes) -> void* {
    void* p = ws + off;
    off += (bytes + 255) & ~(size_t)255;
    return p;
  };
  u16* hln = (u16*)alloc((size_t)8192 * 768 * 2);
  u16* wqkvT = (u16*)alloc((size_t)2304 * 768 * 2);
  u16* wfc1T = (u16*)alloc((size_t)3072 * 768 * 2);
  u16* wfc2T = (u16*)alloc((size_t)768 * 3072 * 2);
  u16* Qb = (u16*)alloc((size_t)B_ * H_ * P_ * HD_ * 2);
  u16* Kb = (u16*)alloc((size_t)B_ * H_ * P_ * HD_ * 2);
  u16* Vtb = (u16*)alloc((size_t)B_ * H_ * HD_ * P_ * 2);
  float* x2 = (float*)alloc((size_t)8192 * 768 * 4);
  u16* O0 = (u16*)alloc((size_t)8192 * 768 * 2);
  u16* O1 = (u16*)alloc((size_t)8192 * 768 * 2);
  u16* gbuf = (u16*)alloc((size_t)8192 * 3072 * 2);

  prep_k<<<14528, 256, 0, stream>>>(wqkv, wqkvT, wfc1, wfc1T, wfc2, wfc2T,
                                    x, ln1w, ln1b, hln);
  gemm_qkv_k<<<dim3(18, 64), 256, 0, stream>>>(hln, wqkvT, bqkv, Qb, Kb, Vtb);
  attn_fused_k<<<256, 768, 0, stream>>>(Qb, Kb, Vtb, O0, O1);
  ln2add_k<<<8192, 256, 0, stream>>>(x, O0, O1, ln2w, ln2b, x2, hln);
  gemm_fc1_k<<<dim3(24, 64), 256, 0, stream>>>(hln, wfc1T, bfc1, gbuf);
  gemm_fc2_k<<<dim3(12, 64), 256, 0, stream>>>(gbuf, wfc2T, bfc2, x2, out);
}